// Round 1
// baseline (191.234 us; speedup 1.0000x reference)
//
#include <hip/hip_runtime.h>
#include <hip/hip_bf16.h>
#include <math.h>

typedef unsigned short u16;
typedef unsigned int u32;
typedef __attribute__((ext_vector_type(8))) short short8;
typedef __attribute__((ext_vector_type(4))) float floatx4;

// Problem constants
constexpr int kB     = 8;
constexpr int kSEQ   = 256;
constexpr int kMEM   = 768;
constexpr int kTOTAL = 1024;  // MEM+SEQ

__device__ __forceinline__ float bf2f(u16 u) {
  return __uint_as_float(((u32)u) << 16);
}
__device__ __forceinline__ u16 f2bf(float f) {
  __hip_bfloat16 h = __float2bfloat16(f);
  return *reinterpret_cast<u16*>(&h);
}
__device__ __forceinline__ void gload_lds16(const u16* g, u16* l) {
  __builtin_amdgcn_global_load_lds(
      (__attribute__((address_space(1))) const unsigned int*)g,
      (__attribute__((address_space(3))) unsigned int*)l, 16, 0, 0);
}

// ---------------------------------------------------------------------------
// Fused prep (one kernel, disjoint block ranges):
//   blocks [0,1024):    Rrel_bf[s,:] = bf16(PE(s)@W_rel); vR[h,s] = 0.125*v·R
//                       (bid 0 also writes u_bf = bf16(0.125*u))
//   blocks [1024,3072): xcat -> bf16
//   blocks [3072,3264): W_qkv^T -> bf16
//   blocks [3264,3328): W_out^T -> bf16
// ---------------------------------------------------------------------------
__device__ __forceinline__ void wtconv_body(
    const float* __restrict__ W, u16* __restrict__ Wt, int K, int N,
    int n0, int k0, int tid, float (*tile)[65])
{
  int r = tid >> 4, c4 = (tid & 15) * 4;
#pragma unroll
  for (int v = 0; v < 4; v++) {
    float4 w4 = *(const float4*)(W + (size_t)(k0 + v * 16 + r) * N + n0 + c4);
    tile[v * 16 + r][c4 + 0] = w4.x;
    tile[v * 16 + r][c4 + 1] = w4.y;
    tile[v * 16 + r][c4 + 2] = w4.z;
    tile[v * 16 + r][c4 + 3] = w4.w;
  }
  __syncthreads();
#pragma unroll
  for (int v = 0; v < 4; v++) {
    int rn = v * 16 + r;
    ushort4 o;
    o.x = f2bf(tile[c4 + 0][rn]);
    o.y = f2bf(tile[c4 + 1][rn]);
    o.z = f2bf(tile[c4 + 2][rn]);
    o.w = f2bf(tile[c4 + 3][rn]);
    *(ushort4*)(Wt + (size_t)(n0 + rn) * K + k0 + c4) = o;
  }
}

__global__ __launch_bounds__(256) void prep_kernel(
    const float* __restrict__ x, const float* __restrict__ memf,
    const float* __restrict__ W_qkv, const float* __restrict__ W_out,
    const float* __restrict__ W_rel, const float* __restrict__ v_emb,
    const float* __restrict__ u_emb,
    u16* __restrict__ Xb, u16* __restrict__ WqkvT, u16* __restrict__ WoutT,
    u16* __restrict__ Rrel_bf, float* __restrict__ vR, u16* __restrict__ u_bf)
{
  __shared__ float tile[64][65];
  __shared__ float pe[22];
  __shared__ float prod[512];
  int bid = blockIdx.x;
  int t = threadIdx.x;
  if (bid < 1024) {
    int s = bid;
    if (bid == 0 && t >= 128 && t < 192) {
      u_bf[t - 128] = f2bf(0.125f * u_emb[t - 128]);
    }
    if (t < 22) {
      int o = (t < 11) ? t : (t - 11);
      float mult = ldexpf(3.14159265358979323846f, o - 10);  // 2^(o-10) * pi
      float ang = (float)s * mult;
      pe[t] = (t < 11) ? sinf(ang) : cosf(ang);
    }
    __syncthreads();
#pragma unroll
    for (int c = 0; c < 2; c++) {
      int j = t + c * 256;
      float acc = 0.f;
#pragma unroll
      for (int o = 0; o < 22; ++o) acc += pe[o] * W_rel[o * 512 + j];
      Rrel_bf[(size_t)s * 512 + j] = f2bf(acc);
      prod[j] = acc * v_emb[j & 63];
    }
    __syncthreads();
    if (t < 8) {
      float a = 0.f;
#pragma unroll 8
      for (int d = 0; d < 64; d++) a += prod[t * 64 + d];
      vR[t * 1024 + s] = a * 0.125f;   // prescaled
    }
  } else if (bid < 3072) {
    int idx = (bid - 1024) * 256 + t;        // 8 elems each
    int row = idx >> 6, c8 = idx & 63;
    int b = row >> 10, pos = row & 1023;
    const float* src = (pos < kMEM)
        ? memf + (size_t)(b * kMEM + pos) * 512
        : x    + (size_t)(b * kSEQ + pos - kMEM) * 512;
    const float4* s4 = (const float4*)(src + c8 * 8);
    float4 a = s4[0], bb = s4[1];
    u16 tmp[8] = {f2bf(a.x),  f2bf(a.y),  f2bf(a.z),  f2bf(a.w),
                  f2bf(bb.x), f2bf(bb.y), f2bf(bb.z), f2bf(bb.w)};
    *(uint4*)(Xb + (size_t)row * 512 + c8 * 8) = *(uint4*)tmp;
  } else if (bid < 3264) {
    int r = bid - 3072;
    wtconv_body(W_qkv, WqkvT, 512, 1536, (r % 24) * 64, (r / 24) * 64, t, tile);
  } else {
    int r = bid - 3264;
    wtconv_body(W_out, WoutT, 512, 512, (r % 8) * 64, (r / 8) * 64, t, tile);
  }
}

// ---------------------------------------------------------------------------
// bf16 MFMA GEMM (qkv): C[M,N] = A[M,K] @ Bt[N,K]^T, bf16 out.  128x128 tile,
// BK=64, XOR-swizzled LDS, bm-fast block remap.  qscale: cols<512 ×0.125.
// ---------------------------------------------------------------------------
__global__ __launch_bounds__(256) void gemm_bf16(
    const u16* __restrict__ A, const u16* __restrict__ Bt,
    int lda, int ldb, int ksteps,
    u16* __restrict__ Cbf, int ldc, int qscale)
{
  __shared__ u16 As[128 * 64];
  __shared__ u16 Bs[128 * 64];
  int tid = threadIdx.x;
  int id = blockIdx.y * gridDim.x + blockIdx.x;
  int gy = gridDim.y;
  int bm = (id % gy) * 128, bn = (id / gy) * 128;
  int ln = tid & 15, quad = (tid >> 4) & 3, w = tid >> 6;
  int moff = (w >> 1) * 64, noff = (w & 1) * 64;
  int l7 = ln & 7;
  floatx4 acc[4][4];
#pragma unroll
  for (int mi = 0; mi < 4; mi++)
#pragma unroll
    for (int ni = 0; ni < 4; ni++) acc[mi][ni] = (floatx4){0.f, 0.f, 0.f, 0.f};

  int srow[4], sgch[4];
#pragma unroll
  for (int v = 0; v < 4; v++) {
    int f = v * 256 + tid;
    srow[v] = f >> 3;
    sgch[v] = (f & 7) ^ ((f >> 3) & 7);
  }

  for (int ks = 0; ks < ksteps; ks++) {
    int k0 = ks * 64;
#pragma unroll
    for (int v = 0; v < 4; v++) {
      gload_lds16(A + (size_t)(bm + srow[v]) * lda + k0 + sgch[v] * 8,
                  &As[(v * 256 + tid) * 8]);
      gload_lds16(Bt + (size_t)(bn + srow[v]) * ldb + k0 + sgch[v] * 8,
                  &Bs[(v * 256 + tid) * 8]);
    }
    __syncthreads();
#pragma unroll
    for (int kb = 0; kb < 2; kb++) {
      short8 af[4], bfr[4];
#pragma unroll
      for (int mi = 0; mi < 4; mi++) {
        int row = moff + mi * 16 + ln;
        af[mi] = *(const short8*)&As[row * 64 + (((quad + 4 * kb) ^ l7) << 3)];
      }
#pragma unroll
      for (int ni = 0; ni < 4; ni++) {
        int row = noff + ni * 16 + ln;
        bfr[ni] = *(const short8*)&Bs[row * 64 + (((quad + 4 * kb) ^ l7) << 3)];
      }
#pragma unroll
      for (int mi = 0; mi < 4; mi++)
#pragma unroll
        for (int ni = 0; ni < 4; ni++)
          acc[mi][ni] = __builtin_amdgcn_mfma_f32_16x16x32_bf16(
              af[mi], bfr[ni], acc[mi][ni], 0, 0, 0);
    }
    __syncthreads();
  }

  int r0 = bm + moff + quad * 4;
#pragma unroll
  for (int ni = 0; ni < 4; ni++) {
    int col = bn + noff + ni * 16 + ln;
    float scale = (qscale && col < 512) ? 0.125f : 1.f;
#pragma unroll
    for (int mi = 0; mi < 4; mi++) {
#pragma unroll
      for (int r = 0; r < 4; r++) {
        int row = r0 + mi * 16 + r;
        Cbf[(size_t)row * ldc + col] = f2bf(acc[mi][ni][r] * scale);
      }
    }
  }
}

// ---------------------------------------------------------------------------
// 64x64-tile bf16 GEMM, fp32 out + bias (output projection).  256 blocks.
// ---------------------------------------------------------------------------
__global__ __launch_bounds__(256) void gemm_bf16_64(
    const u16* __restrict__ A, const u16* __restrict__ Bt,
    int lda, int ldb, int ksteps,
    float* __restrict__ Cf, int ldc, const float* __restrict__ bias)
{
  __shared__ u16 As[64 * 64];
  __shared__ u16 Bs[64 * 64];
  int tid = threadIdx.x;
  int id = blockIdx.y * gridDim.x + blockIdx.x;
  int gy = gridDim.y;
  int bm = (id % gy) * 64, bn = (id / gy) * 64;
  int ln = tid & 15, quad = (tid >> 4) & 3, w = tid >> 6;
  int moff = (w >> 1) * 32, noff = (w & 1) * 32;
  int l7 = ln & 7;
  floatx4 acc[2][2];
#pragma unroll
  for (int mi = 0; mi < 2; mi++)
#pragma unroll
    for (int ni = 0; ni < 2; ni++) acc[mi][ni] = (floatx4){0.f, 0.f, 0.f, 0.f};

  int srow[2], sgch[2];
#pragma unroll
  for (int v = 0; v < 2; v++) {
    int f = v * 256 + tid;
    srow[v] = f >> 3;
    sgch[v] = (f & 7) ^ ((f >> 3) & 7);
  }

  for (int ks = 0; ks < ksteps; ks++) {
    int k0 = ks * 64;
#pragma unroll
    for (int v = 0; v < 2; v++) {
      gload_lds16(A + (size_t)(bm + srow[v]) * lda + k0 + sgch[v] * 8,
                  &As[(v * 256 + tid) * 8]);
      gload_lds16(Bt + (size_t)(bn + srow[v]) * ldb + k0 + sgch[v] * 8,
                  &Bs[(v * 256 + tid) * 8]);
    }
    __syncthreads();
#pragma unroll
    for (int kb = 0; kb < 2; kb++) {
      short8 af[2], bfr[2];
#pragma unroll
      for (int mi = 0; mi < 2; mi++) {
        int row = moff + mi * 16 + ln;
        af[mi] = *(const short8*)&As[row * 64 + (((quad + 4 * kb) ^ l7) << 3)];
      }
#pragma unroll
      for (int ni = 0; ni < 2; ni++) {
        int row = noff + ni * 16 + ln;
        bfr[ni] = *(const short8*)&Bs[row * 64 + (((quad + 4 * kb) ^ l7) << 3)];
      }
#pragma unroll
      for (int mi = 0; mi < 2; mi++)
#pragma unroll
        for (int ni = 0; ni < 2; ni++)
          acc[mi][ni] = __builtin_amdgcn_mfma_f32_16x16x32_bf16(
              af[mi], bfr[ni], acc[mi][ni], 0, 0, 0);
    }
    __syncthreads();
  }

  int r0 = bm + moff + quad * 4;
#pragma unroll
  for (int ni = 0; ni < 2; ni++) {
    int col = bn + noff + ni * 16 + ln;
    float cv = bias[col];
#pragma unroll
    for (int mi = 0; mi < 2; mi++) {
#pragma unroll
      for (int r = 0; r < 4; r++) {
        int row = r0 + mi * 16 + r;
        Cf[(size_t)row * ldc + col] = acc[mi][ni][r] + cv;
      }
    }
  }
}

// ---------------------------------------------------------------------------
// MFMA flash attention v11 = v10 (single-barrier, in-kernel T, fixed-max,
// split-8, in-kernel uk) with the Tl LDS scratchpad replaced by a register
// diagonal-gather:
//   T row il lives entirely in the consumer's own quad (MFMA C-layout:
//   row=4*quad+r, col=l15).  The shifted read T[il][63+il-16ni-l15] is
//   src_lane = 16*quad + ((il+15-l15)&15)   (lane involution, same quad)
//   reg      = tf[3-ni + (l15<il)][il&3]    (condition invariant under the
//                                            involution -> source-side select)
// => 16 cndmask + 16 ds_bpermute per tile instead of 36 LDS u16 ops + 20 f2bf.
// LDS 38400 -> 27648 B: 5 blocks/CU (launch_bounds(256,5) caps VGPR at 102).
// ---------------------------------------------------------------------------
__global__ __launch_bounds__(256, 5) void attn_mfma(
    const u16* __restrict__ qkv_bf, const u16* __restrict__ Rrel_bf,
    const float* __restrict__ vR, const u16* __restrict__ u_bf,
    u16* __restrict__ Opart, float* __restrict__ lbuf)
{
  constexpr int LD = 72;  // Vt/Ps row stride (144 B)
  __shared__ u16 Vt[2][64 * LD];
  __shared__ u16 Ps[64 * LD];

  int nt = blockIdx.x >> 3, p = blockIdx.x & 7;
  int h = blockIdx.y, b = blockIdx.z;
  int n0 = nt * 64, bh = b * 8 + h;
  int tid = threadIdx.x;
  int w = tid >> 6, lane = tid & 63;
  int l15 = lane & 15, quad = lane >> 4, q8 = quad * 8;

  // staging geometry for V
  int sr0 = tid >> 3, sc8 = tid & 7;
  int sr1 = (256 + tid) >> 3;
  int vg0 = ((sr0 >> 3) ^ sc8) * 8 + (sr0 & 7);
  int vg1 = ((sr1 >> 3) ^ sc8) * 8 + (sr1 & 7);

  // ---- Q fragments direct from global (prescaled 0.125) ----
  const u16* qrow = qkv_bf + (size_t)(b * kTOTAL + kMEM + n0 + 16 * w + l15) * 1536 + h * 64;
  short8 qf0 = *(const short8*)(qrow + q8);
  short8 qf1 = *(const short8*)(qrow + 32 + q8);

  // ---- bpermute byte-index for the shifted-T diagonal gather ----
  int bidx[4];
#pragma unroll
  for (int r = 0; r < 4; r++) {
    int il = 4 * quad + r;
    bidx[r] = ((quad << 4) | ((il + 15 - l15) & 15)) << 2;
  }

  const u16* kpart = qkv_bf + (size_t)(b * kTOTAL) * 1536 + 512 + h * 64;
  const float* vRh = vR + h * 1024;

  int ntiles = 13 + nt;
  int mtA = p, mtB = p + 8;
  bool hasB = (mtB < ntiles);
  bool lastB = (mtB == ntiles - 1);

  // ---- stage V for BOTH tiles, single barrier ----
  {
    const u16* va = kpart + (size_t)mtA * 64 * 1536 + 512;
    const u16* vb = kpart + (size_t)mtB * 64 * 1536 + 512;   // in-bounds (mtB<=15)
    uint4 a0 = *(const uint4*)(va + (size_t)sr0 * 1536 + sc8 * 8);
    uint4 a1 = *(const uint4*)(va + (size_t)sr1 * 1536 + sc8 * 8);
    uint4 b0 = *(const uint4*)(vb + (size_t)sr0 * 1536 + sc8 * 8);
    uint4 b1 = *(const uint4*)(vb + (size_t)sr1 * 1536 + sc8 * 8);
    const u16* pa0v = (const u16*)&a0;
    const u16* pa1v = (const u16*)&a1;
    const u16* pb0v = (const u16*)&b0;
    const u16* pb1v = (const u16*)&b1;
#pragma unroll
    for (int i = 0; i < 8; i++) {
      Vt[0][(sc8 * 8 + i) * LD + vg0] = pa0v[i];
      Vt[0][(sc8 * 8 + i) * LD + vg1] = pa1v[i];
      Vt[1][(sc8 * 8 + i) * LD + vg0] = pb0v[i];
      Vt[1][(sc8 * 8 + i) * LD + vg1] = pb1v[i];
    }
  }
  __syncthreads();   // the ONLY barrier

  floatx4 o_acc[4];
  float l_i[4];
#pragma unroll
  for (int r = 0; r < 4; r++) l_i[r] = 0.f;
#pragma unroll
  for (int nd = 0; nd < 4; nd++) o_acc[nd] = (floatx4){0.f, 0.f, 0.f, 0.f};

  int s_base_w = kMEM + n0 + 16 * w;

  auto tile_body = [&](int mt, bool lastt, const u16* VtX) {
    int m0 = mt * 64;
    const u16* kbase = kpart + (size_t)m0 * 1536;
    int sb = s_base_w - m0;

    // K fragments direct from global
    short8 kb0[4], kb1[4];
#pragma unroll
    for (int ni = 0; ni < 4; ni++) {
      const u16* kr = kbase + (size_t)(16 * ni + l15) * 1536;
      kb0[ni] = *(const short8*)(kr + q8);
      kb1[ni] = *(const short8*)(kr + 32 + q8);
    }

    // ---- uk via broadcast-A MFMA: C rows all equal -> keep 1 float per ni ----
    float uk[4];
    {
      short8 uf0 = *(const short8*)(u_bf + q8);
      short8 uf1 = *(const short8*)(u_bf + 32 + q8);
#pragma unroll
      for (int ni = 0; ni < 4; ni++) {
        floatx4 ua = (floatx4){0.f, 0.f, 0.f, 0.f};
        ua = __builtin_amdgcn_mfma_f32_16x16x32_bf16(uf0, kb0[ni], ua, 0, 0, 0);
        ua = __builtin_amdgcn_mfma_f32_16x16x32_bf16(uf1, kb1[ni], ua, 0, 0, 0);
        uk[ni] = ua[0];
      }
    }

    // ---- T = Q @ Rslice^T (+vR), kept in registers (f32, no bf16 rounding) ----
    float tf[5][4];
#pragma unroll
    for (int ct = 0; ct < 5; ct++) {
      int s = sb - 63 + 16 * ct + l15;
      s = min(max(s, 0), 1023);
      const u16* rr = Rrel_bf + (size_t)s * 512 + h * 64;
      short8 rb0 = *(const short8*)(rr + q8);
      short8 rb1 = *(const short8*)(rr + 32 + q8);
      float vv = vRh[s];
      floatx4 t = (floatx4){0.f, 0.f, 0.f, 0.f};
      t = __builtin_amdgcn_mfma_f32_16x16x32_bf16(qf0, rb0, t, 0, 0, 0);
      t = __builtin_amdgcn_mfma_f32_16x16x32_bf16(qf1, rb1, t, 0, 0, 0);
#pragma unroll
      for (int r = 0; r < 4; r++) tf[ct][r] = t[r] + vv;
    }

    // ---- QK^T + logits (+shifted T via bpermute, +uk), p = exp(S) ----
    // ni-outer so s_acc stays a single transient floatx4.
#pragma unroll
    for (int ni = 0; ni < 4; ni++) {
      floatx4 sa = (floatx4){0.f, 0.f, 0.f, 0.f};
      sa = __builtin_amdgcn_mfma_f32_16x16x32_bf16(qf0, kb0[ni], sa, 0, 0, 0);
      sa = __builtin_amdgcn_mfma_f32_16x16x32_bf16(qf1, kb1[ni], sa, 0, 0, 0);
#pragma unroll
      for (int r = 0; r < 4; r++) {
        int il = 4 * quad + r;
        // source-side select (condition invariant under the lane involution)
        float tv = (l15 < il) ? tf[4 - ni][r] : tf[3 - ni][r];
        float tsh = __int_as_float(
            __builtin_amdgcn_ds_bpermute(bidx[r], __float_as_int(tv)));
        float val = sa[r] + tsh + uk[ni];
        if (lastt && (16 * ni + l15) > (16 * w + il)) val = -1e30f;
        float e = __expf(val);
        l_i[r] += e;
        int prow = 16 * w + il;
        Ps[prow * LD + (l15 & 7) + (((2 * ni + (l15 >> 3)) ^ (prow >> 3)) << 3)] =
            f2bf(e);
      }
    }

    // ---- PV (wave-private Ps; V from this tile's LDS buffer) ----
    int rowq = 16 * w + l15, rr3q = rowq >> 3;
    short8 pa0 = *(const short8*)&Ps[rowq * LD + ((quad ^ rr3q) << 3)];
    short8 pa1 = *(const short8*)&Ps[rowq * LD + (((quad + 4) ^ rr3q) << 3)];
#pragma unroll
    for (int nd = 0; nd < 4; nd++) {
      int rowv = 16 * nd + l15, rr3v = rowv >> 3;
      short8 vb0 = *(const short8*)&VtX[rowv * LD + ((quad ^ rr3v) << 3)];
      short8 vb1 = *(const short8*)&VtX[rowv * LD + (((quad + 4) ^ rr3v) << 3)];
      o_acc[nd] = __builtin_amdgcn_mfma_f32_16x16x32_bf16(pa0, vb0, o_acc[nd], 0, 0, 0);
      o_acc[nd] = __builtin_amdgcn_mfma_f32_16x16x32_bf16(pa1, vb1, o_acc[nd], 0, 0, 0);
    }
  };

  tile_body(mtA, false, Vt[0]);        // tile A is never the global last tile
  if (hasB) tile_body(mtB, lastB, Vt[1]);

  // ---- epilogue: butterfly the l partials (once), write O_p + l_p ----
  int pbase = (p * 64 + bh) * 256;
#pragma unroll
  for (int r = 0; r < 4; r++) {
    float l = l_i[r];
#pragma unroll
    for (int off = 1; off < 16; off <<= 1)
      l += __shfl_xor(l, off, 64);
    int n = n0 + 16 * w + 4 * quad + r;
    u16* orow = Opart + ((size_t)(pbase + n) << 6) + l15;
#pragma unroll
    for (int nd = 0; nd < 4; nd++)
      orow[16 * nd] = f2bf(o_acc[nd][r]);
    if (l15 == 0) lbuf[pbase + n] = l;
  }
}

// ---------------------------------------------------------------------------
// Combine the 8 split-m partials: out = Σ_p O_p / Σ_p l_p  (fixed-max).
// ---------------------------------------------------------------------------
__global__ __launch_bounds__(256) void attn_combine(
    const u16* __restrict__ Opart, const float* __restrict__ lbuf,
    u16* __restrict__ aout_bf)
{
  int idx = blockIdx.x * 256 + threadIdx.x;   // 262144
  int bh = idx >> 12, n = (idx >> 4) & 255, d4 = idx & 15;
  int rowi = bh * 256 + n;
  float den = 0.f;
  float num[4] = {0.f, 0.f, 0.f, 0.f};
#pragma unroll
  for (int p = 0; p < 8; p++) {
    den += lbuf[(p << 14) + rowi];
    uint2 raw = *(const uint2*)(Opart + (((size_t)(p << 14) + rowi) << 6) + d4 * 4);
    const u16* us = (const u16*)&raw;
#pragma unroll
    for (int j = 0; j < 4; j++) num[j] += bf2f(us[j]);
  }
  float inv = 1.f / den;
  int b = bh >> 3, h = bh & 7;
  ushort4 o;
  o.x = f2bf(num[0] * inv);
  o.y = f2bf(num[1] * inv);
  o.z = f2bf(num[2] * inv);
  o.w = f2bf(num[3] * inv);
  *(ushort4*)(aout_bf + (size_t)(b * kSEQ + n) * 512 + h * 64 + d4 * 4) = o;
}

// ---------------------------------------------------------------------------
// Host launcher — 5 dispatches.
// ---------------------------------------------------------------------------
extern "C" void kernel_launch(void* const* d_in, const int* in_sizes, int n_in,
                              void* d_out, int out_size, void* d_ws, size_t ws_size,
                              hipStream_t stream) {
  (void)in_sizes; (void)n_in; (void)out_size; (void)ws_size;
  const float* x      = (const float*)d_in[0];
  const float* memory = (const float*)d_in[1];
  const float* W_qkv  = (const float*)d_in[2];
  const float* W_rel  = (const float*)d_in[3];
  const float* W_out  = (const float*)d_in[4];
  const float* b_out  = (const float*)d_in[5];
  const float* u_emb  = (const float*)d_in[6];
  const float* v_emb  = (const float*)d_in[7];
  float* out = (float*)d_out;

  char* ws = (char*)d_ws;
  u16*   qkv_bf  = (u16*)ws;                         ws += (size_t)12582912 * 2;
  u16*   Xcat_bf = (u16*)ws;                         ws += (size_t)4194304 * 2;
  u16*   aout_bf = (u16*)ws;                         ws += (size_t)1048576 * 2;
  u16*   Opart   = (u16*)ws;                         ws += (size_t)8388608 * 2;   // [p<8][bh][n][d]
  float* lbuf    = (float*)ws;                       ws += (size_t)131072 * 4;    // [p<8][bh][n]
  u16*   WqkvT   = (u16*)ws;                         ws += (size_t)786432 * 2;
  u16*   WoutT   = (u16*)ws;                         ws += (size_t)262144 * 2;
  u16*   Rrel_bf = (u16*)ws;                         ws += (size_t)524288 * 2;
  float* vR      = (float*)ws;                       ws += (size_t)8192 * 4;
  u16*   u_bf    = (u16*)ws;                         ws += (size_t)128;
  // total ≈ 57 MB

  // 1. fused prep: Rrel+vR, xcat->bf16, W transposes, u_bf
  prep_kernel<<<3328, 256, 0, stream>>>(
      x, memory, W_qkv, W_out, W_rel, v_emb, u_emb,
      Xcat_bf, WqkvT, WoutT, Rrel_bf, vR, u_bf);

  // 2. qkv = Xcat @ W_qkv  (M=8192, N=1536, K=512), bf16 out, q prescaled
  gemm_bf16<<<dim3(12, 64), 256, 0, stream>>>(
      Xcat_bf, WqkvT, 512, 512, 8, qkv_bf, 1536, 1);

  // 3. attention (uk in-kernel; shifted-T via register bpermute, no Tl LDS)
  attn_mfma<<<dim3(32, 8, 8), 256, 0, stream>>>(
      qkv_bf, Rrel_bf, vR, u_bf, Opart, lbuf);

  // 4. combine split-m partials
  attn_combine<<<1024, 256, 0, stream>>>(Opart, lbuf, aout_bf);

  // 5. out = aout @ W_out + b_out  (M=2048, N=512, K=512), fp32 out, 256 blocks
  gemm_bf16_64<<<dim3(8, 32), 256, 0, stream>>>(
      aout_bf, WoutT, 512, 512, 8, out, 512, b_out);
}

// Round 2
// 166.550 us; speedup vs baseline: 1.1482x; 1.1482x over previous
//
#include <hip/hip_runtime.h>
#include <hip/hip_bf16.h>
#include <math.h>

typedef unsigned short u16;
typedef unsigned int u32;
typedef __attribute__((ext_vector_type(8))) short short8;
typedef __attribute__((ext_vector_type(4))) float floatx4;

// Problem constants
constexpr int kB     = 8;
constexpr int kSEQ   = 256;
constexpr int kMEM   = 768;
constexpr int kTOTAL = 1024;  // MEM+SEQ

__device__ __forceinline__ float bf2f(u16 u) {
  return __uint_as_float(((u32)u) << 16);
}
__device__ __forceinline__ u16 f2bf(float f) {
  __hip_bfloat16 h = __float2bfloat16(f);
  return *reinterpret_cast<u16*>(&h);
}
__device__ __forceinline__ void gload_lds16(const u16* g, u16* l) {
  __builtin_amdgcn_global_load_lds(
      (__attribute__((address_space(1))) const unsigned int*)g,
      (__attribute__((address_space(3))) unsigned int*)l, 16, 0, 0);
}

// ---------------------------------------------------------------------------
// Fused prep (one kernel, disjoint block ranges):
//   blocks [0,1024):    Rrel_bf[s,:] = bf16(PE(s)@W_rel); vR[h,s] = 0.125*v·R
//                       (bid 0 also writes u_bf = bf16(0.125*u))
//   blocks [1024,3072): xcat -> bf16
//   blocks [3072,3264): W_qkv^T -> bf16
//   blocks [3264,3328): W_out^T -> bf16
// ---------------------------------------------------------------------------
__device__ __forceinline__ void wtconv_body(
    const float* __restrict__ W, u16* __restrict__ Wt, int K, int N,
    int n0, int k0, int tid, float (*tile)[65])
{
  int r = tid >> 4, c4 = (tid & 15) * 4;
#pragma unroll
  for (int v = 0; v < 4; v++) {
    float4 w4 = *(const float4*)(W + (size_t)(k0 + v * 16 + r) * N + n0 + c4);
    tile[v * 16 + r][c4 + 0] = w4.x;
    tile[v * 16 + r][c4 + 1] = w4.y;
    tile[v * 16 + r][c4 + 2] = w4.z;
    tile[v * 16 + r][c4 + 3] = w4.w;
  }
  __syncthreads();
#pragma unroll
  for (int v = 0; v < 4; v++) {
    int rn = v * 16 + r;
    ushort4 o;
    o.x = f2bf(tile[c4 + 0][rn]);
    o.y = f2bf(tile[c4 + 1][rn]);
    o.z = f2bf(tile[c4 + 2][rn]);
    o.w = f2bf(tile[c4 + 3][rn]);
    *(ushort4*)(Wt + (size_t)(n0 + rn) * K + k0 + c4) = o;
  }
}

__global__ __launch_bounds__(256) void prep_kernel(
    const float* __restrict__ x, const float* __restrict__ memf,
    const float* __restrict__ W_qkv, const float* __restrict__ W_out,
    const float* __restrict__ W_rel, const float* __restrict__ v_emb,
    const float* __restrict__ u_emb,
    u16* __restrict__ Xb, u16* __restrict__ WqkvT, u16* __restrict__ WoutT,
    u16* __restrict__ Rrel_bf, float* __restrict__ vR, u16* __restrict__ u_bf)
{
  __shared__ float tile[64][65];
  __shared__ float pe[22];
  __shared__ float prod[512];
  int bid = blockIdx.x;
  int t = threadIdx.x;
  if (bid < 1024) {
    int s = bid;
    if (bid == 0 && t >= 128 && t < 192) {
      u_bf[t - 128] = f2bf(0.125f * u_emb[t - 128]);
    }
    if (t < 22) {
      int o = (t < 11) ? t : (t - 11);
      float mult = ldexpf(3.14159265358979323846f, o - 10);  // 2^(o-10) * pi
      float ang = (float)s * mult;
      pe[t] = (t < 11) ? sinf(ang) : cosf(ang);
    }
    __syncthreads();
#pragma unroll
    for (int c = 0; c < 2; c++) {
      int j = t + c * 256;
      float acc = 0.f;
#pragma unroll
      for (int o = 0; o < 22; ++o) acc += pe[o] * W_rel[o * 512 + j];
      Rrel_bf[(size_t)s * 512 + j] = f2bf(acc);
      prod[j] = acc * v_emb[j & 63];
    }
    __syncthreads();
    if (t < 8) {
      float a = 0.f;
#pragma unroll 8
      for (int d = 0; d < 64; d++) a += prod[t * 64 + d];
      vR[t * 1024 + s] = a * 0.125f;   // prescaled
    }
  } else if (bid < 3072) {
    int idx = (bid - 1024) * 256 + t;        // 8 elems each
    int row = idx >> 6, c8 = idx & 63;
    int b = row >> 10, pos = row & 1023;
    const float* src = (pos < kMEM)
        ? memf + (size_t)(b * kMEM + pos) * 512
        : x    + (size_t)(b * kSEQ + pos - kMEM) * 512;
    const float4* s4 = (const float4*)(src + c8 * 8);
    float4 a = s4[0], bb = s4[1];
    u16 tmp[8] = {f2bf(a.x),  f2bf(a.y),  f2bf(a.z),  f2bf(a.w),
                  f2bf(bb.x), f2bf(bb.y), f2bf(bb.z), f2bf(bb.w)};
    *(uint4*)(Xb + (size_t)row * 512 + c8 * 8) = *(uint4*)tmp;
  } else if (bid < 3264) {
    int r = bid - 3072;
    wtconv_body(W_qkv, WqkvT, 512, 1536, (r % 24) * 64, (r / 24) * 64, t, tile);
  } else {
    int r = bid - 3264;
    wtconv_body(W_out, WoutT, 512, 512, (r % 8) * 64, (r / 8) * 64, t, tile);
  }
}

// ---------------------------------------------------------------------------
// bf16 MFMA GEMM (qkv): C[M,N] = A[M,K] @ Bt[N,K]^T, bf16 out.  128x128 tile,
// BK=64, XOR-swizzled LDS, bm-fast block remap.  qscale: cols<512 ×0.125.
// ---------------------------------------------------------------------------
__global__ __launch_bounds__(256) void gemm_bf16(
    const u16* __restrict__ A, const u16* __restrict__ Bt,
    int lda, int ldb, int ksteps,
    u16* __restrict__ Cbf, int ldc, int qscale)
{
  __shared__ u16 As[128 * 64];
  __shared__ u16 Bs[128 * 64];
  int tid = threadIdx.x;
  int id = blockIdx.y * gridDim.x + blockIdx.x;
  int gy = gridDim.y;
  int bm = (id % gy) * 128, bn = (id / gy) * 128;
  int ln = tid & 15, quad = (tid >> 4) & 3, w = tid >> 6;
  int moff = (w >> 1) * 64, noff = (w & 1) * 64;
  int l7 = ln & 7;
  floatx4 acc[4][4];
#pragma unroll
  for (int mi = 0; mi < 4; mi++)
#pragma unroll
    for (int ni = 0; ni < 4; ni++) acc[mi][ni] = (floatx4){0.f, 0.f, 0.f, 0.f};

  int srow[4], sgch[4];
#pragma unroll
  for (int v = 0; v < 4; v++) {
    int f = v * 256 + tid;
    srow[v] = f >> 3;
    sgch[v] = (f & 7) ^ ((f >> 3) & 7);
  }

  for (int ks = 0; ks < ksteps; ks++) {
    int k0 = ks * 64;
#pragma unroll
    for (int v = 0; v < 4; v++) {
      gload_lds16(A + (size_t)(bm + srow[v]) * lda + k0 + sgch[v] * 8,
                  &As[(v * 256 + tid) * 8]);
      gload_lds16(Bt + (size_t)(bn + srow[v]) * ldb + k0 + sgch[v] * 8,
                  &Bs[(v * 256 + tid) * 8]);
    }
    __syncthreads();
#pragma unroll
    for (int kb = 0; kb < 2; kb++) {
      short8 af[4], bfr[4];
#pragma unroll
      for (int mi = 0; mi < 4; mi++) {
        int row = moff + mi * 16 + ln;
        af[mi] = *(const short8*)&As[row * 64 + (((quad + 4 * kb) ^ l7) << 3)];
      }
#pragma unroll
      for (int ni = 0; ni < 4; ni++) {
        int row = noff + ni * 16 + ln;
        bfr[ni] = *(const short8*)&Bs[row * 64 + (((quad + 4 * kb) ^ l7) << 3)];
      }
#pragma unroll
      for (int mi = 0; mi < 4; mi++)
#pragma unroll
        for (int ni = 0; ni < 4; ni++)
          acc[mi][ni] = __builtin_amdgcn_mfma_f32_16x16x32_bf16(
              af[mi], bfr[ni], acc[mi][ni], 0, 0, 0);
    }
    __syncthreads();
  }

  int r0 = bm + moff + quad * 4;
#pragma unroll
  for (int ni = 0; ni < 4; ni++) {
    int col = bn + noff + ni * 16 + ln;
    float scale = (qscale && col < 512) ? 0.125f : 1.f;
#pragma unroll
    for (int mi = 0; mi < 4; mi++) {
#pragma unroll
      for (int r = 0; r < 4; r++) {
        int row = r0 + mi * 16 + r;
        Cbf[(size_t)row * ldc + col] = f2bf(acc[mi][ni][r] * scale);
      }
    }
  }
}

// ---------------------------------------------------------------------------
// 64x64-tile bf16 GEMM, fp32 out + bias (output projection).  256 blocks.
// ---------------------------------------------------------------------------
__global__ __launch_bounds__(256) void gemm_bf16_64(
    const u16* __restrict__ A, const u16* __restrict__ Bt,
    int lda, int ldb, int ksteps,
    float* __restrict__ Cf, int ldc, const float* __restrict__ bias)
{
  __shared__ u16 As[64 * 64];
  __shared__ u16 Bs[64 * 64];
  int tid = threadIdx.x;
  int id = blockIdx.y * gridDim.x + blockIdx.x;
  int gy = gridDim.y;
  int bm = (id % gy) * 64, bn = (id / gy) * 64;
  int ln = tid & 15, quad = (tid >> 4) & 3, w = tid >> 6;
  int moff = (w >> 1) * 32, noff = (w & 1) * 32;
  int l7 = ln & 7;
  floatx4 acc[2][2];
#pragma unroll
  for (int mi = 0; mi < 2; mi++)
#pragma unroll
    for (int ni = 0; ni < 2; ni++) acc[mi][ni] = (floatx4){0.f, 0.f, 0.f, 0.f};

  int srow[2], sgch[2];
#pragma unroll
  for (int v = 0; v < 2; v++) {
    int f = v * 256 + tid;
    srow[v] = f >> 3;
    sgch[v] = (f & 7) ^ ((f >> 3) & 7);
  }

  for (int ks = 0; ks < ksteps; ks++) {
    int k0 = ks * 64;
#pragma unroll
    for (int v = 0; v < 2; v++) {
      gload_lds16(A + (size_t)(bm + srow[v]) * lda + k0 + sgch[v] * 8,
                  &As[(v * 256 + tid) * 8]);
      gload_lds16(Bt + (size_t)(bn + srow[v]) * ldb + k0 + sgch[v] * 8,
                  &Bs[(v * 256 + tid) * 8]);
    }
    __syncthreads();
#pragma unroll
    for (int kb = 0; kb < 2; kb++) {
      short8 af[2], bfr[2];
#pragma unroll
      for (int mi = 0; mi < 2; mi++) {
        int row = moff + mi * 16 + ln;
        af[mi] = *(const short8*)&As[row * 64 + (((quad + 4 * kb) ^ l7) << 3)];
      }
#pragma unroll
      for (int ni = 0; ni < 2; ni++) {
        int row = noff + ni * 16 + ln;
        bfr[ni] = *(const short8*)&Bs[row * 64 + (((quad + 4 * kb) ^ l7) << 3)];
      }
#pragma unroll
      for (int mi = 0; mi < 2; mi++)
#pragma unroll
        for (int ni = 0; ni < 2; ni++)
          acc[mi][ni] = __builtin_amdgcn_mfma_f32_16x16x32_bf16(
              af[mi], bfr[ni], acc[mi][ni], 0, 0, 0);
    }
    __syncthreads();
  }

  int r0 = bm + moff + quad * 4;
#pragma unroll
  for (int ni = 0; ni < 2; ni++) {
    int col = bn + noff + ni * 16 + ln;
    float cv = bias[col];
#pragma unroll
    for (int mi = 0; mi < 2; mi++) {
#pragma unroll
      for (int r = 0; r < 4; r++) {
        int row = r0 + mi * 16 + r;
        Cf[(size_t)row * ldc + col] = acc[mi][ni][r] + cv;
      }
    }
  }
}

// ---------------------------------------------------------------------------
// MFMA flash attention v12 = v11 (Tl LDS scratchpad replaced by register
// diagonal-gather via ds_bpermute) WITHOUT the forced occupancy bound.
// R1 post-mortem: __launch_bounds__(256,5) capped VGPR at ~102 and the
// allocator spilled tf/o_acc/kb to scratch (VGPR_Count 48, WRITE_SIZE
// 17->103 MB = spill stores, FETCH 19->63 MB = spill reloads, dur 52->80us).
// Natural allocation (v10 got 96 VGPR with plain (256)) fits without spill;
// v12 register math vs v10: +20 tf, +4 bidx, -16 uku->uk, -12 s_acc ni-outer.
//   T row il lives entirely in the consumer's own quad (MFMA C-layout:
//   row=4*quad+r, col=l15).  The shifted read T[il][63+il-16ni-l15] is
//   src_lane = 16*quad + ((il+15-l15)&15)   (lane involution, same quad)
//   reg      = tf[3-ni + (l15<il)][il&3]    (condition invariant under the
//                                            involution -> source-side select)
// => 16 cndmask + 16 ds_bpermute per tile instead of 36 LDS u16 ops + 20 f2bf.
// ---------------------------------------------------------------------------
__global__ __launch_bounds__(256) void attn_mfma(
    const u16* __restrict__ qkv_bf, const u16* __restrict__ Rrel_bf,
    const float* __restrict__ vR, const u16* __restrict__ u_bf,
    u16* __restrict__ Opart, float* __restrict__ lbuf)
{
  constexpr int LD = 72;  // Vt/Ps row stride (144 B)
  __shared__ u16 Vt[2][64 * LD];
  __shared__ u16 Ps[64 * LD];

  int nt = blockIdx.x >> 3, p = blockIdx.x & 7;
  int h = blockIdx.y, b = blockIdx.z;
  int n0 = nt * 64, bh = b * 8 + h;
  int tid = threadIdx.x;
  int w = tid >> 6, lane = tid & 63;
  int l15 = lane & 15, quad = lane >> 4, q8 = quad * 8;

  // staging geometry for V
  int sr0 = tid >> 3, sc8 = tid & 7;
  int sr1 = (256 + tid) >> 3;
  int vg0 = ((sr0 >> 3) ^ sc8) * 8 + (sr0 & 7);
  int vg1 = ((sr1 >> 3) ^ sc8) * 8 + (sr1 & 7);

  // ---- Q fragments direct from global (prescaled 0.125) ----
  const u16* qrow = qkv_bf + (size_t)(b * kTOTAL + kMEM + n0 + 16 * w + l15) * 1536 + h * 64;
  short8 qf0 = *(const short8*)(qrow + q8);
  short8 qf1 = *(const short8*)(qrow + 32 + q8);

  // ---- bpermute byte-index for the shifted-T diagonal gather ----
  int bidx[4];
#pragma unroll
  for (int r = 0; r < 4; r++) {
    int il = 4 * quad + r;
    bidx[r] = ((quad << 4) | ((il + 15 - l15) & 15)) << 2;
  }

  const u16* kpart = qkv_bf + (size_t)(b * kTOTAL) * 1536 + 512 + h * 64;
  const float* vRh = vR + h * 1024;

  int ntiles = 13 + nt;
  int mtA = p, mtB = p + 8;
  bool hasB = (mtB < ntiles);
  bool lastB = (mtB == ntiles - 1);

  // ---- stage V for BOTH tiles, single barrier ----
  {
    const u16* va = kpart + (size_t)mtA * 64 * 1536 + 512;
    const u16* vb = kpart + (size_t)mtB * 64 * 1536 + 512;   // in-bounds (mtB<=15)
    uint4 a0 = *(const uint4*)(va + (size_t)sr0 * 1536 + sc8 * 8);
    uint4 a1 = *(const uint4*)(va + (size_t)sr1 * 1536 + sc8 * 8);
    uint4 b0 = *(const uint4*)(vb + (size_t)sr0 * 1536 + sc8 * 8);
    uint4 b1 = *(const uint4*)(vb + (size_t)sr1 * 1536 + sc8 * 8);
    const u16* pa0v = (const u16*)&a0;
    const u16* pa1v = (const u16*)&a1;
    const u16* pb0v = (const u16*)&b0;
    const u16* pb1v = (const u16*)&b1;
#pragma unroll
    for (int i = 0; i < 8; i++) {
      Vt[0][(sc8 * 8 + i) * LD + vg0] = pa0v[i];
      Vt[0][(sc8 * 8 + i) * LD + vg1] = pa1v[i];
      Vt[1][(sc8 * 8 + i) * LD + vg0] = pb0v[i];
      Vt[1][(sc8 * 8 + i) * LD + vg1] = pb1v[i];
    }
  }
  __syncthreads();   // the ONLY barrier

  floatx4 o_acc[4];
  float l_i[4];
#pragma unroll
  for (int r = 0; r < 4; r++) l_i[r] = 0.f;
#pragma unroll
  for (int nd = 0; nd < 4; nd++) o_acc[nd] = (floatx4){0.f, 0.f, 0.f, 0.f};

  int s_base_w = kMEM + n0 + 16 * w;

  auto tile_body = [&](int mt, bool lastt, const u16* VtX) {
    int m0 = mt * 64;
    const u16* kbase = kpart + (size_t)m0 * 1536;
    int sb = s_base_w - m0;

    // K fragments direct from global
    short8 kb0[4], kb1[4];
#pragma unroll
    for (int ni = 0; ni < 4; ni++) {
      const u16* kr = kbase + (size_t)(16 * ni + l15) * 1536;
      kb0[ni] = *(const short8*)(kr + q8);
      kb1[ni] = *(const short8*)(kr + 32 + q8);
    }

    // ---- uk via broadcast-A MFMA: C rows all equal -> keep 1 float per ni ----
    float uk[4];
    {
      short8 uf0 = *(const short8*)(u_bf + q8);
      short8 uf1 = *(const short8*)(u_bf + 32 + q8);
#pragma unroll
      for (int ni = 0; ni < 4; ni++) {
        floatx4 ua = (floatx4){0.f, 0.f, 0.f, 0.f};
        ua = __builtin_amdgcn_mfma_f32_16x16x32_bf16(uf0, kb0[ni], ua, 0, 0, 0);
        ua = __builtin_amdgcn_mfma_f32_16x16x32_bf16(uf1, kb1[ni], ua, 0, 0, 0);
        uk[ni] = ua[0];
      }
    }

    // ---- T = Q @ Rslice^T (+vR), kept in registers (f32, no bf16 rounding) ----
    float tf[5][4];
#pragma unroll
    for (int ct = 0; ct < 5; ct++) {
      int s = sb - 63 + 16 * ct + l15;
      s = min(max(s, 0), 1023);
      const u16* rr = Rrel_bf + (size_t)s * 512 + h * 64;
      short8 rb0 = *(const short8*)(rr + q8);
      short8 rb1 = *(const short8*)(rr + 32 + q8);
      float vv = vRh[s];
      floatx4 t = (floatx4){0.f, 0.f, 0.f, 0.f};
      t = __builtin_amdgcn_mfma_f32_16x16x32_bf16(qf0, rb0, t, 0, 0, 0);
      t = __builtin_amdgcn_mfma_f32_16x16x32_bf16(qf1, rb1, t, 0, 0, 0);
#pragma unroll
      for (int r = 0; r < 4; r++) tf[ct][r] = t[r] + vv;
    }

    // ---- QK^T + logits (+shifted T via bpermute, +uk), p = exp(S) ----
    // ni-outer so s_acc stays a single transient floatx4.
#pragma unroll
    for (int ni = 0; ni < 4; ni++) {
      floatx4 sa = (floatx4){0.f, 0.f, 0.f, 0.f};
      sa = __builtin_amdgcn_mfma_f32_16x16x32_bf16(qf0, kb0[ni], sa, 0, 0, 0);
      sa = __builtin_amdgcn_mfma_f32_16x16x32_bf16(qf1, kb1[ni], sa, 0, 0, 0);
#pragma unroll
      for (int r = 0; r < 4; r++) {
        int il = 4 * quad + r;
        // source-side select (condition invariant under the lane involution)
        float tv = (l15 < il) ? tf[4 - ni][r] : tf[3 - ni][r];
        float tsh = __int_as_float(
            __builtin_amdgcn_ds_bpermute(bidx[r], __float_as_int(tv)));
        float val = sa[r] + tsh + uk[ni];
        if (lastt && (16 * ni + l15) > (16 * w + il)) val = -1e30f;
        float e = __expf(val);
        l_i[r] += e;
        int prow = 16 * w + il;
        Ps[prow * LD + (l15 & 7) + (((2 * ni + (l15 >> 3)) ^ (prow >> 3)) << 3)] =
            f2bf(e);
      }
    }

    // ---- PV (wave-private Ps; V from this tile's LDS buffer) ----
    int rowq = 16 * w + l15, rr3q = rowq >> 3;
    short8 pa0 = *(const short8*)&Ps[rowq * LD + ((quad ^ rr3q) << 3)];
    short8 pa1 = *(const short8*)&Ps[rowq * LD + (((quad + 4) ^ rr3q) << 3)];
#pragma unroll
    for (int nd = 0; nd < 4; nd++) {
      int rowv = 16 * nd + l15, rr3v = rowv >> 3;
      short8 vb0 = *(const short8*)&VtX[rowv * LD + ((quad ^ rr3v) << 3)];
      short8 vb1 = *(const short8*)&VtX[rowv * LD + (((quad + 4) ^ rr3v) << 3)];
      o_acc[nd] = __builtin_amdgcn_mfma_f32_16x16x32_bf16(pa0, vb0, o_acc[nd], 0, 0, 0);
      o_acc[nd] = __builtin_amdgcn_mfma_f32_16x16x32_bf16(pa1, vb1, o_acc[nd], 0, 0, 0);
    }
  };

  tile_body(mtA, false, Vt[0]);        // tile A is never the global last tile
  if (hasB) tile_body(mtB, lastB, Vt[1]);

  // ---- epilogue: butterfly the l partials (once), write O_p + l_p ----
  int pbase = (p * 64 + bh) * 256;
#pragma unroll
  for (int r = 0; r < 4; r++) {
    float l = l_i[r];
#pragma unroll
    for (int off = 1; off < 16; off <<= 1)
      l += __shfl_xor(l, off, 64);
    int n = n0 + 16 * w + 4 * quad + r;
    u16* orow = Opart + ((size_t)(pbase + n) << 6) + l15;
#pragma unroll
    for (int nd = 0; nd < 4; nd++)
      orow[16 * nd] = f2bf(o_acc[nd][r]);
    if (l15 == 0) lbuf[pbase + n] = l;
  }
}

// ---------------------------------------------------------------------------
// Combine the 8 split-m partials: out = Σ_p O_p / Σ_p l_p  (fixed-max).
// ---------------------------------------------------------------------------
__global__ __launch_bounds__(256) void attn_combine(
    const u16* __restrict__ Opart, const float* __restrict__ lbuf,
    u16* __restrict__ aout_bf)
{
  int idx = blockIdx.x * 256 + threadIdx.x;   // 262144
  int bh = idx >> 12, n = (idx >> 4) & 255, d4 = idx & 15;
  int rowi = bh * 256 + n;
  float den = 0.f;
  float num[4] = {0.f, 0.f, 0.f, 0.f};
#pragma unroll
  for (int p = 0; p < 8; p++) {
    den += lbuf[(p << 14) + rowi];
    uint2 raw = *(const uint2*)(Opart + (((size_t)(p << 14) + rowi) << 6) + d4 * 4);
    const u16* us = (const u16*)&raw;
#pragma unroll
    for (int j = 0; j < 4; j++) num[j] += bf2f(us[j]);
  }
  float inv = 1.f / den;
  int b = bh >> 3, h = bh & 7;
  ushort4 o;
  o.x = f2bf(num[0] * inv);
  o.y = f2bf(num[1] * inv);
  o.z = f2bf(num[2] * inv);
  o.w = f2bf(num[3] * inv);
  *(ushort4*)(aout_bf + (size_t)(b * kSEQ + n) * 512 + h * 64 + d4 * 4) = o;
}

// ---------------------------------------------------------------------------
// Host launcher — 5 dispatches.
// ---------------------------------------------------------------------------
extern "C" void kernel_launch(void* const* d_in, const int* in_sizes, int n_in,
                              void* d_out, int out_size, void* d_ws, size_t ws_size,
                              hipStream_t stream) {
  (void)in_sizes; (void)n_in; (void)out_size; (void)ws_size;
  const float* x      = (const float*)d_in[0];
  const float* memory = (const float*)d_in[1];
  const float* W_qkv  = (const float*)d_in[2];
  const float* W_rel  = (const float*)d_in[3];
  const float* W_out  = (const float*)d_in[4];
  const float* b_out  = (const float*)d_in[5];
  const float* u_emb  = (const float*)d_in[6];
  const float* v_emb  = (const float*)d_in[7];
  float* out = (float*)d_out;

  char* ws = (char*)d_ws;
  u16*   qkv_bf  = (u16*)ws;                         ws += (size_t)12582912 * 2;
  u16*   Xcat_bf = (u16*)ws;                         ws += (size_t)4194304 * 2;
  u16*   aout_bf = (u16*)ws;                         ws += (size_t)1048576 * 2;
  u16*   Opart   = (u16*)ws;                         ws += (size_t)8388608 * 2;   // [p<8][bh][n][d]
  float* lbuf    = (float*)ws;                       ws += (size_t)131072 * 4;    // [p<8][bh][n]
  u16*   WqkvT   = (u16*)ws;                         ws += (size_t)786432 * 2;
  u16*   WoutT   = (u16*)ws;                         ws += (size_t)262144 * 2;
  u16*   Rrel_bf = (u16*)ws;                         ws += (size_t)524288 * 2;
  float* vR      = (float*)ws;                       ws += (size_t)8192 * 4;
  u16*   u_bf    = (u16*)ws;                         ws += (size_t)128;
  // total ≈ 57 MB

  // 1. fused prep: Rrel+vR, xcat->bf16, W transposes, u_bf
  prep_kernel<<<3328, 256, 0, stream>>>(
      x, memory, W_qkv, W_out, W_rel, v_emb, u_emb,
      Xcat_bf, WqkvT, WoutT, Rrel_bf, vR, u_bf);

  // 2. qkv = Xcat @ W_qkv  (M=8192, N=1536, K=512), bf16 out, q prescaled
  gemm_bf16<<<dim3(12, 64), 256, 0, stream>>>(
      Xcat_bf, WqkvT, 512, 512, 8, qkv_bf, 1536, 1);

  // 3. attention (uk in-kernel; shifted-T via register bpermute, no Tl LDS)
  attn_mfma<<<dim3(32, 8, 8), 256, 0, stream>>>(
      qkv_bf, Rrel_bf, vR, u_bf, Opart, lbuf);

  // 4. combine split-m partials
  attn_combine<<<1024, 256, 0, stream>>>(Opart, lbuf, aout_bf);

  // 5. out = aout @ W_out + b_out  (M=2048, N=512, K=512), fp32 out, 256 blocks
  gemm_bf16_64<<<dim3(8, 32), 256, 0, stream>>>(
      aout_bf, WoutT, 512, 512, 8, out, 512, b_out);
}

// Round 3
// 157.651 us; speedup vs baseline: 1.2130x; 1.0564x over previous
//
#include <hip/hip_runtime.h>
#include <hip/hip_bf16.h>
#include <math.h>

typedef unsigned short u16;
typedef unsigned int u32;
typedef __attribute__((ext_vector_type(8))) short short8;
typedef __attribute__((ext_vector_type(4))) float floatx4;

// Problem constants
constexpr int kB     = 8;
constexpr int kSEQ   = 256;
constexpr int kMEM   = 768;
constexpr int kTOTAL = 1024;  // MEM+SEQ

__device__ __forceinline__ float bf2f(u16 u) {
  return __uint_as_float(((u32)u) << 16);
}
__device__ __forceinline__ u16 f2bf(float f) {
  __hip_bfloat16 h = __float2bfloat16(f);
  return *reinterpret_cast<u16*>(&h);
}
__device__ __forceinline__ void gload_lds16(const u16* g, u16* l) {
  __builtin_amdgcn_global_load_lds(
      (__attribute__((address_space(1))) const unsigned int*)g,
      (__attribute__((address_space(3))) unsigned int*)l, 16, 0, 0);
}

// ---------------------------------------------------------------------------
// Fused prep (one kernel, disjoint block ranges):
//   blocks [0,1024):    Rrel_bf[s,:] = bf16(PE(s)@W_rel);
//                       vR'[h,s] = 0.125*(v·R_f32 - u·R_bf16)
//                       (u-part uses ROUNDED R so it exactly cancels the u·R
//                        term that the u-folded Q introduces in T' = (q+u)·R)
//   blocks [1024,3072): xcat -> bf16
//   blocks [3072,3264): W_qkv^T -> bf16
//   blocks [3264,3328): W_out^T -> bf16
// ---------------------------------------------------------------------------
__device__ __forceinline__ void wtconv_body(
    const float* __restrict__ W, u16* __restrict__ Wt, int K, int N,
    int n0, int k0, int tid, float (*tile)[65])
{
  int r = tid >> 4, c4 = (tid & 15) * 4;
#pragma unroll
  for (int v = 0; v < 4; v++) {
    float4 w4 = *(const float4*)(W + (size_t)(k0 + v * 16 + r) * N + n0 + c4);
    tile[v * 16 + r][c4 + 0] = w4.x;
    tile[v * 16 + r][c4 + 1] = w4.y;
    tile[v * 16 + r][c4 + 2] = w4.z;
    tile[v * 16 + r][c4 + 3] = w4.w;
  }
  __syncthreads();
#pragma unroll
  for (int v = 0; v < 4; v++) {
    int rn = v * 16 + r;
    ushort4 o;
    o.x = f2bf(tile[c4 + 0][rn]);
    o.y = f2bf(tile[c4 + 1][rn]);
    o.z = f2bf(tile[c4 + 2][rn]);
    o.w = f2bf(tile[c4 + 3][rn]);
    *(ushort4*)(Wt + (size_t)(n0 + rn) * K + k0 + c4) = o;
  }
}

__global__ __launch_bounds__(256) void prep_kernel(
    const float* __restrict__ x, const float* __restrict__ memf,
    const float* __restrict__ W_qkv, const float* __restrict__ W_out,
    const float* __restrict__ W_rel, const float* __restrict__ v_emb,
    const float* __restrict__ u_emb,
    u16* __restrict__ Xb, u16* __restrict__ WqkvT, u16* __restrict__ WoutT,
    u16* __restrict__ Rrel_bf, float* __restrict__ vR)
{
  __shared__ float tile[64][65];
  __shared__ float pe[22];
  __shared__ float prod[512];
  int bid = blockIdx.x;
  int t = threadIdx.x;
  if (bid < 1024) {
    int s = bid;
    if (t < 22) {
      int o = (t < 11) ? t : (t - 11);
      float mult = ldexpf(3.14159265358979323846f, o - 10);  // 2^(o-10) * pi
      float ang = (float)s * mult;
      pe[t] = (t < 11) ? sinf(ang) : cosf(ang);
    }
    __syncthreads();
#pragma unroll
    for (int c = 0; c < 2; c++) {
      int j = t + c * 256;
      float acc = 0.f;
#pragma unroll
      for (int o = 0; o < 22; ++o) acc += pe[o] * W_rel[o * 512 + j];
      u16 rbf = f2bf(acc);
      Rrel_bf[(size_t)s * 512 + j] = rbf;
      // v-part uses f32 R (matches reference term_d); u-part uses the ROUNDED
      // R so it cancels the u·R_bf16 embedded in T' = (q+u)_bf16 · R_bf16.
      prod[j] = acc * v_emb[j & 63] - bf2f(rbf) * u_emb[j & 63];
    }
    __syncthreads();
    if (t < 8) {
      float a = 0.f;
#pragma unroll 8
      for (int d = 0; d < 64; d++) a += prod[t * 64 + d];
      vR[t * 1024 + s] = a * 0.125f;   // prescaled
    }
  } else if (bid < 3072) {
    int idx = (bid - 1024) * 256 + t;        // 8 elems each
    int row = idx >> 6, c8 = idx & 63;
    int b = row >> 10, pos = row & 1023;
    const float* src = (pos < kMEM)
        ? memf + (size_t)(b * kMEM + pos) * 512
        : x    + (size_t)(b * kSEQ + pos - kMEM) * 512;
    const float4* s4 = (const float4*)(src + c8 * 8);
    float4 a = s4[0], bb = s4[1];
    u16 tmp[8] = {f2bf(a.x),  f2bf(a.y),  f2bf(a.z),  f2bf(a.w),
                  f2bf(bb.x), f2bf(bb.y), f2bf(bb.z), f2bf(bb.w)};
    *(uint4*)(Xb + (size_t)row * 512 + c8 * 8) = *(uint4*)tmp;
  } else if (bid < 3264) {
    int r = bid - 3072;
    wtconv_body(W_qkv, WqkvT, 512, 1536, (r % 24) * 64, (r / 24) * 64, t, tile);
  } else {
    int r = bid - 3264;
    wtconv_body(W_out, WoutT, 512, 512, (r % 8) * 64, (r / 8) * 64, t, tile);
  }
}

// ---------------------------------------------------------------------------
// bf16 MFMA GEMM (qkv): C[M,N] = A[M,K] @ Bt[N,K]^T, bf16 out.  128x128 tile,
// BK=64, XOR-swizzled LDS, bm-fast block remap.
// qscale: cols<512 (the q third) -> out = (acc + u[col&63]) * 0.125
// (u-fold: term_a + term_c = (q+u)·k, so q' = 0.125(q_raw + u)).
// ---------------------------------------------------------------------------
__global__ __launch_bounds__(256) void gemm_bf16(
    const u16* __restrict__ A, const u16* __restrict__ Bt,
    int lda, int ldb, int ksteps,
    u16* __restrict__ Cbf, int ldc, int qscale, const float* __restrict__ uq)
{
  __shared__ u16 As[128 * 64];
  __shared__ u16 Bs[128 * 64];
  int tid = threadIdx.x;
  int id = blockIdx.y * gridDim.x + blockIdx.x;
  int gy = gridDim.y;
  int bm = (id % gy) * 128, bn = (id / gy) * 128;
  int ln = tid & 15, quad = (tid >> 4) & 3, w = tid >> 6;
  int moff = (w >> 1) * 64, noff = (w & 1) * 64;
  int l7 = ln & 7;
  floatx4 acc[4][4];
#pragma unroll
  for (int mi = 0; mi < 4; mi++)
#pragma unroll
    for (int ni = 0; ni < 4; ni++) acc[mi][ni] = (floatx4){0.f, 0.f, 0.f, 0.f};

  int srow[4], sgch[4];
#pragma unroll
  for (int v = 0; v < 4; v++) {
    int f = v * 256 + tid;
    srow[v] = f >> 3;
    sgch[v] = (f & 7) ^ ((f >> 3) & 7);
  }

  for (int ks = 0; ks < ksteps; ks++) {
    int k0 = ks * 64;
#pragma unroll
    for (int v = 0; v < 4; v++) {
      gload_lds16(A + (size_t)(bm + srow[v]) * lda + k0 + sgch[v] * 8,
                  &As[(v * 256 + tid) * 8]);
      gload_lds16(Bt + (size_t)(bn + srow[v]) * ldb + k0 + sgch[v] * 8,
                  &Bs[(v * 256 + tid) * 8]);
    }
    __syncthreads();
#pragma unroll
    for (int kb = 0; kb < 2; kb++) {
      short8 af[4], bfr[4];
#pragma unroll
      for (int mi = 0; mi < 4; mi++) {
        int row = moff + mi * 16 + ln;
        af[mi] = *(const short8*)&As[row * 64 + (((quad + 4 * kb) ^ l7) << 3)];
      }
#pragma unroll
      for (int ni = 0; ni < 4; ni++) {
        int row = noff + ni * 16 + ln;
        bfr[ni] = *(const short8*)&Bs[row * 64 + (((quad + 4 * kb) ^ l7) << 3)];
      }
#pragma unroll
      for (int mi = 0; mi < 4; mi++)
#pragma unroll
        for (int ni = 0; ni < 4; ni++)
          acc[mi][ni] = __builtin_amdgcn_mfma_f32_16x16x32_bf16(
              af[mi], bfr[ni], acc[mi][ni], 0, 0, 0);
    }
    __syncthreads();
  }

  int r0 = bm + moff + quad * 4;
#pragma unroll
  for (int ni = 0; ni < 4; ni++) {
    int col = bn + noff + ni * 16 + ln;
    bool isq = qscale && col < 512;
    float scale = isq ? 0.125f : 1.f;
    float uadd = isq ? uq[col & 63] : 0.f;
#pragma unroll
    for (int mi = 0; mi < 4; mi++) {
#pragma unroll
      for (int r = 0; r < 4; r++) {
        int row = r0 + mi * 16 + r;
        Cbf[(size_t)row * ldc + col] = f2bf((acc[mi][ni][r] + uadd) * scale);
      }
    }
  }
}

// ---------------------------------------------------------------------------
// 64x64-tile bf16 GEMM, fp32 out + bias (output projection).  256 blocks.
// ---------------------------------------------------------------------------
__global__ __launch_bounds__(256) void gemm_bf16_64(
    const u16* __restrict__ A, const u16* __restrict__ Bt,
    int lda, int ldb, int ksteps,
    float* __restrict__ Cf, int ldc, const float* __restrict__ bias)
{
  __shared__ u16 As[64 * 64];
  __shared__ u16 Bs[64 * 64];
  int tid = threadIdx.x;
  int id = blockIdx.y * gridDim.x + blockIdx.x;
  int gy = gridDim.y;
  int bm = (id % gy) * 64, bn = (id / gy) * 64;
  int ln = tid & 15, quad = (tid >> 4) & 3, w = tid >> 6;
  int moff = (w >> 1) * 32, noff = (w & 1) * 32;
  int l7 = ln & 7;
  floatx4 acc[2][2];
#pragma unroll
  for (int mi = 0; mi < 2; mi++)
#pragma unroll
    for (int ni = 0; ni < 2; ni++) acc[mi][ni] = (floatx4){0.f, 0.f, 0.f, 0.f};

  int srow[2], sgch[2];
#pragma unroll
  for (int v = 0; v < 2; v++) {
    int f = v * 256 + tid;
    srow[v] = f >> 3;
    sgch[v] = (f & 7) ^ ((f >> 3) & 7);
  }

  for (int ks = 0; ks < ksteps; ks++) {
    int k0 = ks * 64;
#pragma unroll
    for (int v = 0; v < 2; v++) {
      gload_lds16(A + (size_t)(bm + srow[v]) * lda + k0 + sgch[v] * 8,
                  &As[(v * 256 + tid) * 8]);
      gload_lds16(Bt + (size_t)(bn + srow[v]) * ldb + k0 + sgch[v] * 8,
                  &Bs[(v * 256 + tid) * 8]);
    }
    __syncthreads();
#pragma unroll
    for (int kb = 0; kb < 2; kb++) {
      short8 af[2], bfr[2];
#pragma unroll
      for (int mi = 0; mi < 2; mi++) {
        int row = moff + mi * 16 + ln;
        af[mi] = *(const short8*)&As[row * 64 + (((quad + 4 * kb) ^ l7) << 3)];
      }
#pragma unroll
      for (int ni = 0; ni < 2; ni++) {
        int row = noff + ni * 16 + ln;
        bfr[ni] = *(const short8*)&Bs[row * 64 + (((quad + 4 * kb) ^ l7) << 3)];
      }
#pragma unroll
      for (int mi = 0; mi < 2; mi++)
#pragma unroll
        for (int ni = 0; ni < 2; ni++)
          acc[mi][ni] = __builtin_amdgcn_mfma_f32_16x16x32_bf16(
              af[mi], bfr[ni], acc[mi][ni], 0, 0, 0);
    }
    __syncthreads();
  }

  int r0 = bm + moff + quad * 4;
#pragma unroll
  for (int ni = 0; ni < 2; ni++) {
    int col = bn + noff + ni * 16 + ln;
    float cv = bias[col];
#pragma unroll
    for (int mi = 0; mi < 2; mi++) {
#pragma unroll
      for (int r = 0; r < 4; r++) {
        int row = r0 + mi * 16 + r;
        Cf[(size_t)row * ldc + col] = acc[mi][ni][r] + cv;
      }
    }
  }
}

// ---------------------------------------------------------------------------
// MFMA flash attention v13:
//  - u folded into q at the qkv GEMM (term_c gone: no uk MFMAs, no u_bf);
//    the spurious u·R in T' is cancelled by vR' (see prep).  26 MFMA/tile.
//  - tsh diagonal-gather BATCHED between T and QK: all 16 cndmask+bpermute
//    issue together, their lgkm latency overlaps the QK MFMAs, and the
//    logits loop is pure add→exp→store (v12's regression was the bpermute
//    sitting inside the per-ni MFMA→exp dependence chain: VALUBusy 20→34%).
//   T row il lives entirely in the consumer's own quad (MFMA C-layout:
//   row=4*quad+r, col=l15).  The shifted read T[il][63+il-16ni-l15] is
//   src_lane = 16*quad + ((il+15-l15)&15)   (lane involution, same quad)
//   reg      = tf[3-ni + (l15<il)][il&3]    (condition invariant under the
//                                            involution -> source-side select)
// ---------------------------------------------------------------------------
__global__ __launch_bounds__(256) void attn_mfma(
    const u16* __restrict__ qkv_bf, const u16* __restrict__ Rrel_bf,
    const float* __restrict__ vR,
    u16* __restrict__ Opart, float* __restrict__ lbuf)
{
  constexpr int LD = 72;  // Vt/Ps row stride (144 B)
  __shared__ u16 Vt[2][64 * LD];
  __shared__ u16 Ps[64 * LD];

  int nt = blockIdx.x >> 3, p = blockIdx.x & 7;
  int h = blockIdx.y, b = blockIdx.z;
  int n0 = nt * 64, bh = b * 8 + h;
  int tid = threadIdx.x;
  int w = tid >> 6, lane = tid & 63;
  int l15 = lane & 15, quad = lane >> 4, q8 = quad * 8;

  // staging geometry for V
  int sr0 = tid >> 3, sc8 = tid & 7;
  int sr1 = (256 + tid) >> 3;
  int vg0 = ((sr0 >> 3) ^ sc8) * 8 + (sr0 & 7);
  int vg1 = ((sr1 >> 3) ^ sc8) * 8 + (sr1 & 7);

  // ---- Q fragments direct from global (prescaled 0.125, u folded in) ----
  const u16* qrow = qkv_bf + (size_t)(b * kTOTAL + kMEM + n0 + 16 * w + l15) * 1536 + h * 64;
  short8 qf0 = *(const short8*)(qrow + q8);
  short8 qf1 = *(const short8*)(qrow + 32 + q8);

  // ---- bpermute byte-index for the shifted-T diagonal gather ----
  int bidx[4];
#pragma unroll
  for (int r = 0; r < 4; r++) {
    int il = 4 * quad + r;
    bidx[r] = ((quad << 4) | ((il + 15 - l15) & 15)) << 2;
  }

  const u16* kpart = qkv_bf + (size_t)(b * kTOTAL) * 1536 + 512 + h * 64;
  const float* vRh = vR + h * 1024;

  int ntiles = 13 + nt;
  int mtA = p, mtB = p + 8;
  bool hasB = (mtB < ntiles);
  bool lastB = (mtB == ntiles - 1);

  // ---- stage V for BOTH tiles, single barrier ----
  {
    const u16* va = kpart + (size_t)mtA * 64 * 1536 + 512;
    const u16* vb = kpart + (size_t)mtB * 64 * 1536 + 512;   // in-bounds (mtB<=15)
    uint4 a0 = *(const uint4*)(va + (size_t)sr0 * 1536 + sc8 * 8);
    uint4 a1 = *(const uint4*)(va + (size_t)sr1 * 1536 + sc8 * 8);
    uint4 b0 = *(const uint4*)(vb + (size_t)sr0 * 1536 + sc8 * 8);
    uint4 b1 = *(const uint4*)(vb + (size_t)sr1 * 1536 + sc8 * 8);
    const u16* pa0v = (const u16*)&a0;
    const u16* pa1v = (const u16*)&a1;
    const u16* pb0v = (const u16*)&b0;
    const u16* pb1v = (const u16*)&b1;
#pragma unroll
    for (int i = 0; i < 8; i++) {
      Vt[0][(sc8 * 8 + i) * LD + vg0] = pa0v[i];
      Vt[0][(sc8 * 8 + i) * LD + vg1] = pa1v[i];
      Vt[1][(sc8 * 8 + i) * LD + vg0] = pb0v[i];
      Vt[1][(sc8 * 8 + i) * LD + vg1] = pb1v[i];
    }
  }
  __syncthreads();   // the ONLY barrier

  floatx4 o_acc[4];
  float l_i[4];
#pragma unroll
  for (int r = 0; r < 4; r++) l_i[r] = 0.f;
#pragma unroll
  for (int nd = 0; nd < 4; nd++) o_acc[nd] = (floatx4){0.f, 0.f, 0.f, 0.f};

  int s_base_w = kMEM + n0 + 16 * w;

  auto tile_body = [&](int mt, bool lastt, const u16* VtX) {
    int m0 = mt * 64;
    const u16* kbase = kpart + (size_t)m0 * 1536;
    int sb = s_base_w - m0;

    // K fragments direct from global; first consumer is QK (after T+tsh),
    // so ~15 MFMAs + the bpermute block cover their latency.
    short8 kb0[4], kb1[4];
#pragma unroll
    for (int ni = 0; ni < 4; ni++) {
      const u16* kr = kbase + (size_t)(16 * ni + l15) * 1536;
      kb0[ni] = *(const short8*)(kr + q8);
      kb1[ni] = *(const short8*)(kr + 32 + q8);
    }

    // ---- T = Q @ Rslice^T (+vR'), kept in registers (f32) ----
    float tf[5][4];
#pragma unroll
    for (int ct = 0; ct < 5; ct++) {
      int s = sb - 63 + 16 * ct + l15;
      s = min(max(s, 0), 1023);
      const u16* rr = Rrel_bf + (size_t)s * 512 + h * 64;
      short8 rb0 = *(const short8*)(rr + q8);
      short8 rb1 = *(const short8*)(rr + 32 + q8);
      float vv = vRh[s];
      floatx4 t = (floatx4){0.f, 0.f, 0.f, 0.f};
      t = __builtin_amdgcn_mfma_f32_16x16x32_bf16(qf0, rb0, t, 0, 0, 0);
      t = __builtin_amdgcn_mfma_f32_16x16x32_bf16(qf1, rb1, t, 0, 0, 0);
#pragma unroll
      for (int r = 0; r < 4; r++) tf[ct][r] = t[r] + vv;
    }

    // ---- shifted-T diagonal gather, BATCHED (tf dies here) ----
    float tsh[4][4];
#pragma unroll
    for (int ni = 0; ni < 4; ni++) {
#pragma unroll
      for (int r = 0; r < 4; r++) {
        int il = 4 * quad + r;
        float tv = (l15 < il) ? tf[4 - ni][r] : tf[3 - ni][r];
        tsh[ni][r] = __int_as_float(
            __builtin_amdgcn_ds_bpermute(bidx[r], __float_as_int(tv)));
      }
    }

    // ---- QK^T, batched (8 MFMAs back-to-back; bpermutes drain under them) --
    floatx4 sa[4];
#pragma unroll
    for (int ni = 0; ni < 4; ni++) {
      floatx4 s4 = (floatx4){0.f, 0.f, 0.f, 0.f};
      s4 = __builtin_amdgcn_mfma_f32_16x16x32_bf16(qf0, kb0[ni], s4, 0, 0, 0);
      s4 = __builtin_amdgcn_mfma_f32_16x16x32_bf16(qf1, kb1[ni], s4, 0, 0, 0);
      sa[ni] = s4;
    }

    // ---- logits: pure add -> exp -> store ----
#pragma unroll
    for (int ni = 0; ni < 4; ni++) {
#pragma unroll
      for (int r = 0; r < 4; r++) {
        int il = 4 * quad + r;
        float val = sa[ni][r] + tsh[ni][r];
        if (lastt && (16 * ni + l15) > (16 * w + il)) val = -1e30f;
        float e = __expf(val);
        l_i[r] += e;
        int prow = 16 * w + il;
        Ps[prow * LD + (l15 & 7) + (((2 * ni + (l15 >> 3)) ^ (prow >> 3)) << 3)] =
            f2bf(e);
      }
    }

    // ---- PV (wave-private Ps; V from this tile's LDS buffer) ----
    int rowq = 16 * w + l15, rr3q = rowq >> 3;
    short8 pa0 = *(const short8*)&Ps[rowq * LD + ((quad ^ rr3q) << 3)];
    short8 pa1 = *(const short8*)&Ps[rowq * LD + (((quad + 4) ^ rr3q) << 3)];
#pragma unroll
    for (int nd = 0; nd < 4; nd++) {
      int rowv = 16 * nd + l15, rr3v = rowv >> 3;
      short8 vb0 = *(const short8*)&VtX[rowv * LD + ((quad ^ rr3v) << 3)];
      short8 vb1 = *(const short8*)&VtX[rowv * LD + (((quad + 4) ^ rr3v) << 3)];
      o_acc[nd] = __builtin_amdgcn_mfma_f32_16x16x32_bf16(pa0, vb0, o_acc[nd], 0, 0, 0);
      o_acc[nd] = __builtin_amdgcn_mfma_f32_16x16x32_bf16(pa1, vb1, o_acc[nd], 0, 0, 0);
    }
  };

  tile_body(mtA, false, Vt[0]);        // tile A is never the global last tile
  if (hasB) tile_body(mtB, lastB, Vt[1]);

  // ---- epilogue: butterfly the l partials (once), write O_p + l_p ----
  int pbase = (p * 64 + bh) * 256;
#pragma unroll
  for (int r = 0; r < 4; r++) {
    float l = l_i[r];
#pragma unroll
    for (int off = 1; off < 16; off <<= 1)
      l += __shfl_xor(l, off, 64);
    int n = n0 + 16 * w + 4 * quad + r;
    u16* orow = Opart + ((size_t)(pbase + n) << 6) + l15;
#pragma unroll
    for (int nd = 0; nd < 4; nd++)
      orow[16 * nd] = f2bf(o_acc[nd][r]);
    if (l15 == 0) lbuf[pbase + n] = l;
  }
}

// ---------------------------------------------------------------------------
// Combine the 8 split-m partials: out = Σ_p O_p / Σ_p l_p  (fixed-max).
// ---------------------------------------------------------------------------
__global__ __launch_bounds__(256) void attn_combine(
    const u16* __restrict__ Opart, const float* __restrict__ lbuf,
    u16* __restrict__ aout_bf)
{
  int idx = blockIdx.x * 256 + threadIdx.x;   // 262144
  int bh = idx >> 12, n = (idx >> 4) & 255, d4 = idx & 15;
  int rowi = bh * 256 + n;
  float den = 0.f;
  float num[4] = {0.f, 0.f, 0.f, 0.f};
#pragma unroll
  for (int p = 0; p < 8; p++) {
    den += lbuf[(p << 14) + rowi];
    uint2 raw = *(const uint2*)(Opart + (((size_t)(p << 14) + rowi) << 6) + d4 * 4);
    const u16* us = (const u16*)&raw;
#pragma unroll
    for (int j = 0; j < 4; j++) num[j] += bf2f(us[j]);
  }
  float inv = 1.f / den;
  int b = bh >> 3, h = bh & 7;
  ushort4 o;
  o.x = f2bf(num[0] * inv);
  o.y = f2bf(num[1] * inv);
  o.z = f2bf(num[2] * inv);
  o.w = f2bf(num[3] * inv);
  *(ushort4*)(aout_bf + (size_t)(b * kSEQ + n) * 512 + h * 64 + d4 * 4) = o;
}

// ---------------------------------------------------------------------------
// Host launcher — 5 dispatches.
// ---------------------------------------------------------------------------
extern "C" void kernel_launch(void* const* d_in, const int* in_sizes, int n_in,
                              void* d_out, int out_size, void* d_ws, size_t ws_size,
                              hipStream_t stream) {
  (void)in_sizes; (void)n_in; (void)out_size; (void)ws_size;
  const float* x      = (const float*)d_in[0];
  const float* memory = (const float*)d_in[1];
  const float* W_qkv  = (const float*)d_in[2];
  const float* W_rel  = (const float*)d_in[3];
  const float* W_out  = (const float*)d_in[4];
  const float* b_out  = (const float*)d_in[5];
  const float* u_emb  = (const float*)d_in[6];
  const float* v_emb  = (const float*)d_in[7];
  float* out = (float*)d_out;

  char* ws = (char*)d_ws;
  u16*   qkv_bf  = (u16*)ws;                         ws += (size_t)12582912 * 2;
  u16*   Xcat_bf = (u16*)ws;                         ws += (size_t)4194304 * 2;
  u16*   aout_bf = (u16*)ws;                         ws += (size_t)1048576 * 2;
  u16*   Opart   = (u16*)ws;                         ws += (size_t)8388608 * 2;   // [p<8][bh][n][d]
  float* lbuf    = (float*)ws;                       ws += (size_t)131072 * 4;    // [p<8][bh][n]
  u16*   WqkvT   = (u16*)ws;                         ws += (size_t)786432 * 2;
  u16*   WoutT   = (u16*)ws;                         ws += (size_t)262144 * 2;
  u16*   Rrel_bf = (u16*)ws;                         ws += (size_t)524288 * 2;
  float* vR      = (float*)ws;                       ws += (size_t)8192 * 4;
  // total ≈ 57 MB

  // 1. fused prep: Rrel + vR' (u-compensated), xcat->bf16, W transposes
  prep_kernel<<<3328, 256, 0, stream>>>(
      x, memory, W_qkv, W_out, W_rel, v_emb, u_emb,
      Xcat_bf, WqkvT, WoutT, Rrel_bf, vR);

  // 2. qkv = Xcat @ W_qkv  (M=8192, N=1536, K=512), bf16 out,
  //    q third gets (acc + u)*0.125 (u-fold)
  gemm_bf16<<<dim3(12, 64), 256, 0, stream>>>(
      Xcat_bf, WqkvT, 512, 512, 8, qkv_bf, 1536, 1, u_emb);

  // 3. attention (term_c folded into q; shifted-T via batched bpermute)
  attn_mfma<<<dim3(32, 8, 8), 256, 0, stream>>>(
      qkv_bf, Rrel_bf, vR, Opart, lbuf);

  // 4. combine split-m partials
  attn_combine<<<1024, 256, 0, stream>>>(Opart, lbuf, aout_bf);

  // 5. out = aout @ W_out + b_out  (M=2048, N=512, K=512), fp32 out, 256 blocks
  gemm_bf16_64<<<dim3(8, 32), 256, 0, stream>>>(
      aout_bf, WoutT, 512, 512, 8, out, 512, b_out);
}

// Round 4
// 153.081 us; speedup vs baseline: 1.2492x; 1.0298x over previous
//
#include <hip/hip_runtime.h>
#include <hip/hip_bf16.h>
#include <math.h>

typedef unsigned short u16;
typedef unsigned int u32;
typedef __attribute__((ext_vector_type(8))) short short8;
typedef __attribute__((ext_vector_type(4))) float floatx4;

// Problem constants
constexpr int kB     = 8;
constexpr int kSEQ   = 256;
constexpr int kMEM   = 768;
constexpr int kTOTAL = 1024;  // MEM+SEQ

__device__ __forceinline__ float bf2f(u16 u) {
  return __uint_as_float(((u32)u) << 16);
}
__device__ __forceinline__ u16 f2bf(float f) {
  __hip_bfloat16 h = __float2bfloat16(f);
  return *reinterpret_cast<u16*>(&h);
}
__device__ __forceinline__ void gload_lds16(const u16* g, u16* l) {
  __builtin_amdgcn_global_load_lds(
      (__attribute__((address_space(1))) const unsigned int*)g,
      (__attribute__((address_space(3))) unsigned int*)l, 16, 0, 0);
}

// ---------------------------------------------------------------------------
// Fused prep (one kernel, disjoint block ranges):
//   blocks [0,1024):    Rrel_bf[s,:] = bf16(PE(s)@W_rel);
//                       vR'[h,s] = 0.125*(v·R_f32 - u·R_bf16)
//                       (u-part uses ROUNDED R so it exactly cancels the u·R
//                        term that the u-folded Q introduces in T' = (q+u)·R)
//   blocks [1024,3072): xcat -> bf16
//   blocks [3072,3264): W_qkv^T -> bf16
//   blocks [3264,3328): W_out^T -> bf16
// ---------------------------------------------------------------------------
__device__ __forceinline__ void wtconv_body(
    const float* __restrict__ W, u16* __restrict__ Wt, int K, int N,
    int n0, int k0, int tid, float (*tile)[65])
{
  int r = tid >> 4, c4 = (tid & 15) * 4;
#pragma unroll
  for (int v = 0; v < 4; v++) {
    float4 w4 = *(const float4*)(W + (size_t)(k0 + v * 16 + r) * N + n0 + c4);
    tile[v * 16 + r][c4 + 0] = w4.x;
    tile[v * 16 + r][c4 + 1] = w4.y;
    tile[v * 16 + r][c4 + 2] = w4.z;
    tile[v * 16 + r][c4 + 3] = w4.w;
  }
  __syncthreads();
#pragma unroll
  for (int v = 0; v < 4; v++) {
    int rn = v * 16 + r;
    ushort4 o;
    o.x = f2bf(tile[c4 + 0][rn]);
    o.y = f2bf(tile[c4 + 1][rn]);
    o.z = f2bf(tile[c4 + 2][rn]);
    o.w = f2bf(tile[c4 + 3][rn]);
    *(ushort4*)(Wt + (size_t)(n0 + rn) * K + k0 + c4) = o;
  }
}

__global__ __launch_bounds__(256) void prep_kernel(
    const float* __restrict__ x, const float* __restrict__ memf,
    const float* __restrict__ W_qkv, const float* __restrict__ W_out,
    const float* __restrict__ W_rel, const float* __restrict__ v_emb,
    const float* __restrict__ u_emb,
    u16* __restrict__ Xb, u16* __restrict__ WqkvT, u16* __restrict__ WoutT,
    u16* __restrict__ Rrel_bf, float* __restrict__ vR)
{
  __shared__ float tile[64][65];
  __shared__ float pe[22];
  __shared__ float prod[512];
  int bid = blockIdx.x;
  int t = threadIdx.x;
  if (bid < 1024) {
    int s = bid;
    if (t < 22) {
      int o = (t < 11) ? t : (t - 11);
      float mult = ldexpf(3.14159265358979323846f, o - 10);  // 2^(o-10) * pi
      float ang = (float)s * mult;
      pe[t] = (t < 11) ? sinf(ang) : cosf(ang);
    }
    __syncthreads();
#pragma unroll
    for (int c = 0; c < 2; c++) {
      int j = t + c * 256;
      float acc = 0.f;
#pragma unroll
      for (int o = 0; o < 22; ++o) acc += pe[o] * W_rel[o * 512 + j];
      u16 rbf = f2bf(acc);
      Rrel_bf[(size_t)s * 512 + j] = rbf;
      // v-part uses f32 R (matches reference term_d); u-part uses the ROUNDED
      // R so it cancels the u·R_bf16 embedded in T' = (q+u)_bf16 · R_bf16.
      prod[j] = acc * v_emb[j & 63] - bf2f(rbf) * u_emb[j & 63];
    }
    __syncthreads();
    if (t < 8) {
      float a = 0.f;
#pragma unroll 8
      for (int d = 0; d < 64; d++) a += prod[t * 64 + d];
      vR[t * 1024 + s] = a * 0.125f;   // prescaled
    }
  } else if (bid < 3072) {
    int idx = (bid - 1024) * 256 + t;        // 8 elems each
    int row = idx >> 6, c8 = idx & 63;
    int b = row >> 10, pos = row & 1023;
    const float* src = (pos < kMEM)
        ? memf + (size_t)(b * kMEM + pos) * 512
        : x    + (size_t)(b * kSEQ + pos - kMEM) * 512;
    const float4* s4 = (const float4*)(src + c8 * 8);
    float4 a = s4[0], bb = s4[1];
    u16 tmp[8] = {f2bf(a.x),  f2bf(a.y),  f2bf(a.z),  f2bf(a.w),
                  f2bf(bb.x), f2bf(bb.y), f2bf(bb.z), f2bf(bb.w)};
    *(uint4*)(Xb + (size_t)row * 512 + c8 * 8) = *(uint4*)tmp;
  } else if (bid < 3264) {
    int r = bid - 3072;
    wtconv_body(W_qkv, WqkvT, 512, 1536, (r % 24) * 64, (r / 24) * 64, t, tile);
  } else {
    int r = bid - 3264;
    wtconv_body(W_out, WoutT, 512, 512, (r % 8) * 64, (r / 8) * 64, t, tile);
  }
}

// ---------------------------------------------------------------------------
// bf16 MFMA GEMM (qkv): C[M,N] = A[M,K] @ Bt[N,K]^T, bf16 out.  128x128 tile,
// BK=64, XOR-swizzled LDS, bm-fast block remap.
// qscale: cols<512 (the q third) -> out = (acc + u[col&63]) * 0.125
// (u-fold: term_a + term_c = (q+u)·k, so q' = 0.125(q_raw + u)).
// ---------------------------------------------------------------------------
__global__ __launch_bounds__(256) void gemm_bf16(
    const u16* __restrict__ A, const u16* __restrict__ Bt,
    int lda, int ldb, int ksteps,
    u16* __restrict__ Cbf, int ldc, int qscale, const float* __restrict__ uq)
{
  __shared__ u16 As[128 * 64];
  __shared__ u16 Bs[128 * 64];
  int tid = threadIdx.x;
  int id = blockIdx.y * gridDim.x + blockIdx.x;
  int gy = gridDim.y;
  int bm = (id % gy) * 128, bn = (id / gy) * 128;
  int ln = tid & 15, quad = (tid >> 4) & 3, w = tid >> 6;
  int moff = (w >> 1) * 64, noff = (w & 1) * 64;
  int l7 = ln & 7;
  floatx4 acc[4][4];
#pragma unroll
  for (int mi = 0; mi < 4; mi++)
#pragma unroll
    for (int ni = 0; ni < 4; ni++) acc[mi][ni] = (floatx4){0.f, 0.f, 0.f, 0.f};

  int srow[4], sgch[4];
#pragma unroll
  for (int v = 0; v < 4; v++) {
    int f = v * 256 + tid;
    srow[v] = f >> 3;
    sgch[v] = (f & 7) ^ ((f >> 3) & 7);
  }

  for (int ks = 0; ks < ksteps; ks++) {
    int k0 = ks * 64;
#pragma unroll
    for (int v = 0; v < 4; v++) {
      gload_lds16(A + (size_t)(bm + srow[v]) * lda + k0 + sgch[v] * 8,
                  &As[(v * 256 + tid) * 8]);
      gload_lds16(Bt + (size_t)(bn + srow[v]) * ldb + k0 + sgch[v] * 8,
                  &Bs[(v * 256 + tid) * 8]);
    }
    __syncthreads();
#pragma unroll
    for (int kb = 0; kb < 2; kb++) {
      short8 af[4], bfr[4];
#pragma unroll
      for (int mi = 0; mi < 4; mi++) {
        int row = moff + mi * 16 + ln;
        af[mi] = *(const short8*)&As[row * 64 + (((quad + 4 * kb) ^ l7) << 3)];
      }
#pragma unroll
      for (int ni = 0; ni < 4; ni++) {
        int row = noff + ni * 16 + ln;
        bfr[ni] = *(const short8*)&Bs[row * 64 + (((quad + 4 * kb) ^ l7) << 3)];
      }
#pragma unroll
      for (int mi = 0; mi < 4; mi++)
#pragma unroll
        for (int ni = 0; ni < 4; ni++)
          acc[mi][ni] = __builtin_amdgcn_mfma_f32_16x16x32_bf16(
              af[mi], bfr[ni], acc[mi][ni], 0, 0, 0);
    }
    __syncthreads();
  }

  int r0 = bm + moff + quad * 4;
#pragma unroll
  for (int ni = 0; ni < 4; ni++) {
    int col = bn + noff + ni * 16 + ln;
    bool isq = qscale && col < 512;
    float scale = isq ? 0.125f : 1.f;
    float uadd = isq ? uq[col & 63] : 0.f;
#pragma unroll
    for (int mi = 0; mi < 4; mi++) {
#pragma unroll
      for (int r = 0; r < 4; r++) {
        int row = r0 + mi * 16 + r;
        Cbf[(size_t)row * ldc + col] = f2bf((acc[mi][ni][r] + uadd) * scale);
      }
    }
  }
}

// ---------------------------------------------------------------------------
// 64x64-tile bf16 GEMM, fp32 out + bias (output projection).  256 blocks.
// ---------------------------------------------------------------------------
__global__ __launch_bounds__(256) void gemm_bf16_64(
    const u16* __restrict__ A, const u16* __restrict__ Bt,
    int lda, int ldb, int ksteps,
    float* __restrict__ Cf, int ldc, const float* __restrict__ bias)
{
  __shared__ u16 As[64 * 64];
  __shared__ u16 Bs[64 * 64];
  int tid = threadIdx.x;
  int id = blockIdx.y * gridDim.x + blockIdx.x;
  int gy = gridDim.y;
  int bm = (id % gy) * 64, bn = (id / gy) * 64;
  int ln = tid & 15, quad = (tid >> 4) & 3, w = tid >> 6;
  int moff = (w >> 1) * 32, noff = (w & 1) * 32;
  int l7 = ln & 7;
  floatx4 acc[2][2];
#pragma unroll
  for (int mi = 0; mi < 2; mi++)
#pragma unroll
    for (int ni = 0; ni < 2; ni++) acc[mi][ni] = (floatx4){0.f, 0.f, 0.f, 0.f};

  int srow[2], sgch[2];
#pragma unroll
  for (int v = 0; v < 2; v++) {
    int f = v * 256 + tid;
    srow[v] = f >> 3;
    sgch[v] = (f & 7) ^ ((f >> 3) & 7);
  }

  for (int ks = 0; ks < ksteps; ks++) {
    int k0 = ks * 64;
#pragma unroll
    for (int v = 0; v < 2; v++) {
      gload_lds16(A + (size_t)(bm + srow[v]) * lda + k0 + sgch[v] * 8,
                  &As[(v * 256 + tid) * 8]);
      gload_lds16(Bt + (size_t)(bn + srow[v]) * ldb + k0 + sgch[v] * 8,
                  &Bs[(v * 256 + tid) * 8]);
    }
    __syncthreads();
#pragma unroll
    for (int kb = 0; kb < 2; kb++) {
      short8 af[2], bfr[2];
#pragma unroll
      for (int mi = 0; mi < 2; mi++) {
        int row = moff + mi * 16 + ln;
        af[mi] = *(const short8*)&As[row * 64 + (((quad + 4 * kb) ^ l7) << 3)];
      }
#pragma unroll
      for (int ni = 0; ni < 2; ni++) {
        int row = noff + ni * 16 + ln;
        bfr[ni] = *(const short8*)&Bs[row * 64 + (((quad + 4 * kb) ^ l7) << 3)];
      }
#pragma unroll
      for (int mi = 0; mi < 2; mi++)
#pragma unroll
        for (int ni = 0; ni < 2; ni++)
          acc[mi][ni] = __builtin_amdgcn_mfma_f32_16x16x32_bf16(
              af[mi], bfr[ni], acc[mi][ni], 0, 0, 0);
    }
    __syncthreads();
  }

  int r0 = bm + moff + quad * 4;
#pragma unroll
  for (int ni = 0; ni < 2; ni++) {
    int col = bn + noff + ni * 16 + ln;
    float cv = bias[col];
#pragma unroll
    for (int mi = 0; mi < 2; mi++) {
#pragma unroll
      for (int r = 0; r < 4; r++) {
        int row = r0 + mi * 16 + r;
        Cf[(size_t)row * ldc + col] = acc[mi][ni][r] + cv;
      }
    }
  }
}

// ---------------------------------------------------------------------------
// MFMA flash attention v14 = v13 software-pipelined.
// R3 post-mortem: all pipes idle (MFMA 4.4%, VALU 35%, HBM 8.7%), 125k cyc/CU
// for ~2k cyc/block of issue work => bound by serialized vmcnt segments.
// Fixes:
//  - ALL tile-A loads (K,R,vR) issue BEFORE the barrier: the compiler must
//    emit s_waitcnt vmcnt(0) before s_barrier anyway, so their latency rides
//    the V-staging drain for free.
//  - tile B fully pipelined into tile A: R-B/vR-B issue after tsh-A (covered
//    by QK-A+logits-A), K-B after logits-A (covered by T-B+tsh-B+PV-A), and
//    T-B/tsh-B run between logits-A's Ps writes and PV-A's Ps reads (covers
//    the LDS write->read turnaround).
//  - tile B unconditional: the causal mask generalizes to
//    (16ni+l15) > sb+il  (== old last-tile mask when sb=16w; never true for
//    interior tiles; ALWAYS true for phantom tiles p+8>=ntiles, whose
//    contribution is then exactly exp(-1e30)=0).  mtB<=15 is memory-safe.
// ---------------------------------------------------------------------------
__global__ __launch_bounds__(256) void attn_mfma(
    const u16* __restrict__ qkv_bf, const u16* __restrict__ Rrel_bf,
    const float* __restrict__ vR,
    u16* __restrict__ Opart, float* __restrict__ lbuf)
{
  constexpr int LD = 72;  // Vt/Ps row stride (144 B)
  __shared__ u16 Vt[2][64 * LD];
  __shared__ u16 Ps[64 * LD];

  int nt = blockIdx.x >> 3, p = blockIdx.x & 7;
  int h = blockIdx.y, b = blockIdx.z;
  int n0 = nt * 64, bh = b * 8 + h;
  int tid = threadIdx.x;
  int w = tid >> 6, lane = tid & 63;
  int l15 = lane & 15, quad = lane >> 4, q8 = quad * 8;

  // staging geometry for V
  int sr0 = tid >> 3, sc8 = tid & 7;
  int sr1 = (256 + tid) >> 3;
  int vg0 = ((sr0 >> 3) ^ sc8) * 8 + (sr0 & 7);
  int vg1 = ((sr1 >> 3) ^ sc8) * 8 + (sr1 & 7);

  const u16* kpart = qkv_bf + (size_t)(b * kTOTAL) * 1536 + 512 + h * 64;
  const float* vRh = vR + h * 1024;

  int mtA = p, mtB = p + 8;             // mtB<=15: memory-safe even if phantom
  int m0A = mtA * 64, m0B = mtB * 64;
  int s_base_w = kMEM + n0 + 16 * w;
  int sbA = s_base_w - m0A, sbB = s_base_w - m0B;

  // ==== issue ALL pre-barrier loads (drained by the barrier's vmcnt(0)) ====
  // V for both tiles
  const u16* va = kpart + (size_t)mtA * 64 * 1536 + 512;
  const u16* vb = kpart + (size_t)mtB * 64 * 1536 + 512;
  uint4 a0 = *(const uint4*)(va + (size_t)sr0 * 1536 + sc8 * 8);
  uint4 a1 = *(const uint4*)(va + (size_t)sr1 * 1536 + sc8 * 8);
  uint4 b0 = *(const uint4*)(vb + (size_t)sr0 * 1536 + sc8 * 8);
  uint4 b1 = *(const uint4*)(vb + (size_t)sr1 * 1536 + sc8 * 8);

  // Q fragments (prescaled 0.125, u folded in)
  const u16* qrow = qkv_bf + (size_t)(b * kTOTAL + kMEM + n0 + 16 * w + l15) * 1536 + h * 64;
  short8 qf0 = *(const short8*)(qrow + q8);
  short8 qf1 = *(const short8*)(qrow + 32 + q8);

  // K-A fragments
  short8 kbA0[4], kbA1[4];
#pragma unroll
  for (int ni = 0; ni < 4; ni++) {
    const u16* kr = kpart + (size_t)(m0A + 16 * ni + l15) * 1536;
    kbA0[ni] = *(const short8*)(kr + q8);
    kbA1[ni] = *(const short8*)(kr + 32 + q8);
  }

  // R-A fragments + vR-A
  short8 rbA0[5], rbA1[5];
  float vRcA[5];
#pragma unroll
  for (int ct = 0; ct < 5; ct++) {
    int s = sbA - 63 + 16 * ct + l15;
    s = min(max(s, 0), 1023);
    const u16* rr = Rrel_bf + (size_t)s * 512 + h * 64;
    rbA0[ct] = *(const short8*)(rr + q8);
    rbA1[ct] = *(const short8*)(rr + 32 + q8);
    vRcA[ct] = vRh[s];
  }

  // bpermute byte-index for the shifted-T diagonal gather
  int bidx[4];
#pragma unroll
  for (int r = 0; r < 4; r++) {
    int il = 4 * quad + r;
    bidx[r] = ((quad << 4) | ((il + 15 - l15) & 15)) << 2;
  }

  // V LDS writes (both tiles)
  {
    const u16* pa0v = (const u16*)&a0;
    const u16* pa1v = (const u16*)&a1;
    const u16* pb0v = (const u16*)&b0;
    const u16* pb1v = (const u16*)&b1;
#pragma unroll
    for (int i = 0; i < 8; i++) {
      Vt[0][(sc8 * 8 + i) * LD + vg0] = pa0v[i];
      Vt[0][(sc8 * 8 + i) * LD + vg1] = pa1v[i];
      Vt[1][(sc8 * 8 + i) * LD + vg0] = pb0v[i];
      Vt[1][(sc8 * 8 + i) * LD + vg1] = pb1v[i];
    }
  }
  __syncthreads();   // the ONLY barrier; drains every load issued above

  floatx4 o_acc[4];
  float l_i[4];
#pragma unroll
  for (int r = 0; r < 4; r++) l_i[r] = 0.f;
#pragma unroll
  for (int nd = 0; nd < 4; nd++) o_acc[nd] = (floatx4){0.f, 0.f, 0.f, 0.f};

  // ---- phase helpers (all fully inlined, static indices) ----
  auto do_T = [&](short8 (&rb0)[5], short8 (&rb1)[5], float (&vRc)[5],
                  float (&tf)[5][4]) {
#pragma unroll
    for (int ct = 0; ct < 5; ct++) {
      floatx4 t = (floatx4){0.f, 0.f, 0.f, 0.f};
      t = __builtin_amdgcn_mfma_f32_16x16x32_bf16(qf0, rb0[ct], t, 0, 0, 0);
      t = __builtin_amdgcn_mfma_f32_16x16x32_bf16(qf1, rb1[ct], t, 0, 0, 0);
#pragma unroll
      for (int r = 0; r < 4; r++) tf[ct][r] = t[r] + vRc[ct];
    }
  };
  auto do_tsh = [&](float (&tf)[5][4], float (&tsh)[4][4]) {
#pragma unroll
    for (int ni = 0; ni < 4; ni++) {
#pragma unroll
      for (int r = 0; r < 4; r++) {
        int il = 4 * quad + r;
        float tv = (l15 < il) ? tf[4 - ni][r] : tf[3 - ni][r];
        tsh[ni][r] = __int_as_float(
            __builtin_amdgcn_ds_bpermute(bidx[r], __float_as_int(tv)));
      }
    }
  };
  auto do_QK = [&](short8 (&kb0)[4], short8 (&kb1)[4], floatx4 (&sa)[4]) {
#pragma unroll
    for (int ni = 0; ni < 4; ni++) {
      floatx4 s4 = (floatx4){0.f, 0.f, 0.f, 0.f};
      s4 = __builtin_amdgcn_mfma_f32_16x16x32_bf16(qf0, kb0[ni], s4, 0, 0, 0);
      s4 = __builtin_amdgcn_mfma_f32_16x16x32_bf16(qf1, kb1[ni], s4, 0, 0, 0);
      sa[ni] = s4;
    }
  };
  auto do_logits = [&](floatx4 (&sa)[4], float (&tsh)[4][4], int sb) {
#pragma unroll
    for (int ni = 0; ni < 4; ni++) {
#pragma unroll
      for (int r = 0; r < 4; r++) {
        int il = 4 * quad + r;
        float val = sa[ni][r] + tsh[ni][r];
        if ((16 * ni + l15) > (sb + il)) val = -1e30f;   // generalized causal mask
        float e = __expf(val);
        l_i[r] += e;
        int prow = 16 * w + il;
        Ps[prow * LD + (l15 & 7) + (((2 * ni + (l15 >> 3)) ^ (prow >> 3)) << 3)] =
            f2bf(e);
      }
    }
  };
  auto do_PV = [&](const u16* VtX) {
    int rowq = 16 * w + l15, rr3q = rowq >> 3;
    short8 pa0 = *(const short8*)&Ps[rowq * LD + ((quad ^ rr3q) << 3)];
    short8 pa1 = *(const short8*)&Ps[rowq * LD + (((quad + 4) ^ rr3q) << 3)];
#pragma unroll
    for (int nd = 0; nd < 4; nd++) {
      int rowv = 16 * nd + l15, rr3v = rowv >> 3;
      short8 vb0 = *(const short8*)&VtX[rowv * LD + ((quad ^ rr3v) << 3)];
      short8 vb1 = *(const short8*)&VtX[rowv * LD + (((quad + 4) ^ rr3v) << 3)];
      o_acc[nd] = __builtin_amdgcn_mfma_f32_16x16x32_bf16(pa0, vb0, o_acc[nd], 0, 0, 0);
      o_acc[nd] = __builtin_amdgcn_mfma_f32_16x16x32_bf16(pa1, vb1, o_acc[nd], 0, 0, 0);
    }
  };

  // ==== pipelined schedule ====
  // tile A front (all operands pre-drained: zero vmem stalls)
  float tfA[5][4];
  do_T(rbA0, rbA1, vRcA, tfA);
  float tshA[4][4];
  do_tsh(tfA, tshA);

  // issue R-B + vR-B (cover: QK-A + logits-A)
  short8 rbB0[5], rbB1[5];
  float vRcB[5];
#pragma unroll
  for (int ct = 0; ct < 5; ct++) {
    int s = sbB - 63 + 16 * ct + l15;
    s = min(max(s, 0), 1023);
    const u16* rr = Rrel_bf + (size_t)s * 512 + h * 64;
    rbB0[ct] = *(const short8*)(rr + q8);
    rbB1[ct] = *(const short8*)(rr + 32 + q8);
    vRcB[ct] = vRh[s];
  }

  floatx4 saA[4];
  do_QK(kbA0, kbA1, saA);
  do_logits(saA, tshA, sbA);

  // issue K-B (cover: T-B + tsh-B + PV-A)
  short8 kbB0[4], kbB1[4];
#pragma unroll
  for (int ni = 0; ni < 4; ni++) {
    const u16* kr = kpart + (size_t)(m0B + 16 * ni + l15) * 1536;
    kbB0[ni] = *(const short8*)(kr + q8);
    kbB1[ni] = *(const short8*)(kr + 32 + q8);
  }

  // tile B front between Ps-A writes and Ps-A reads (covers LDS turnaround)
  float tfB[5][4];
  do_T(rbB0, rbB1, vRcB, tfB);
  float tshB[4][4];
  do_tsh(tfB, tshB);

  do_PV(Vt[0]);                 // tile A close

  floatx4 saB[4];
  do_QK(kbB0, kbB1, saB);
  do_logits(saB, tshB, sbB);
  do_PV(Vt[1]);                 // tile B close

  // ---- epilogue: butterfly the l partials (once), write O_p + l_p ----
  int pbase = (p * 64 + bh) * 256;
#pragma unroll
  for (int r = 0; r < 4; r++) {
    float l = l_i[r];
#pragma unroll
    for (int off = 1; off < 16; off <<= 1)
      l += __shfl_xor(l, off, 64);
    int n = n0 + 16 * w + 4 * quad + r;
    u16* orow = Opart + ((size_t)(pbase + n) << 6) + l15;
#pragma unroll
    for (int nd = 0; nd < 4; nd++)
      orow[16 * nd] = f2bf(o_acc[nd][r]);
    if (l15 == 0) lbuf[pbase + n] = l;
  }
}

// ---------------------------------------------------------------------------
// Combine the 8 split-m partials: out = Σ_p O_p / Σ_p l_p  (fixed-max).
// ---------------------------------------------------------------------------
__global__ __launch_bounds__(256) void attn_combine(
    const u16* __restrict__ Opart, const float* __restrict__ lbuf,
    u16* __restrict__ aout_bf)
{
  int idx = blockIdx.x * 256 + threadIdx.x;   // 262144
  int bh = idx >> 12, n = (idx >> 4) & 255, d4 = idx & 15;
  int rowi = bh * 256 + n;
  float den = 0.f;
  float num[4] = {0.f, 0.f, 0.f, 0.f};
#pragma unroll
  for (int p = 0; p < 8; p++) {
    den += lbuf[(p << 14) + rowi];
    uint2 raw = *(const uint2*)(Opart + (((size_t)(p << 14) + rowi) << 6) + d4 * 4);
    const u16* us = (const u16*)&raw;
#pragma unroll
    for (int j = 0; j < 4; j++) num[j] += bf2f(us[j]);
  }
  float inv = 1.f / den;
  int b = bh >> 3, h = bh & 7;
  ushort4 o;
  o.x = f2bf(num[0] * inv);
  o.y = f2bf(num[1] * inv);
  o.z = f2bf(num[2] * inv);
  o.w = f2bf(num[3] * inv);
  *(ushort4*)(aout_bf + (size_t)(b * kSEQ + n) * 512 + h * 64 + d4 * 4) = o;
}

// ---------------------------------------------------------------------------
// Host launcher — 5 dispatches.
// ---------------------------------------------------------------------------
extern "C" void kernel_launch(void* const* d_in, const int* in_sizes, int n_in,
                              void* d_out, int out_size, void* d_ws, size_t ws_size,
                              hipStream_t stream) {
  (void)in_sizes; (void)n_in; (void)out_size; (void)ws_size;
  const float* x      = (const float*)d_in[0];
  const float* memory = (const float*)d_in[1];
  const float* W_qkv  = (const float*)d_in[2];
  const float* W_rel  = (const float*)d_in[3];
  const float* W_out  = (const float*)d_in[4];
  const float* b_out  = (const float*)d_in[5];
  const float* u_emb  = (const float*)d_in[6];
  const float* v_emb  = (const float*)d_in[7];
  float* out = (float*)d_out;

  char* ws = (char*)d_ws;
  u16*   qkv_bf  = (u16*)ws;                         ws += (size_t)12582912 * 2;
  u16*   Xcat_bf = (u16*)ws;                         ws += (size_t)4194304 * 2;
  u16*   aout_bf = (u16*)ws;                         ws += (size_t)1048576 * 2;
  u16*   Opart   = (u16*)ws;                         ws += (size_t)8388608 * 2;   // [p<8][bh][n][d]
  float* lbuf    = (float*)ws;                       ws += (size_t)131072 * 4;    // [p<8][bh][n]
  u16*   WqkvT   = (u16*)ws;                         ws += (size_t)786432 * 2;
  u16*   WoutT   = (u16*)ws;                         ws += (size_t)262144 * 2;
  u16*   Rrel_bf = (u16*)ws;                         ws += (size_t)524288 * 2;
  float* vR      = (float*)ws;                       ws += (size_t)8192 * 4;
  // total ≈ 57 MB

  // 1. fused prep: Rrel + vR' (u-compensated), xcat->bf16, W transposes
  prep_kernel<<<3328, 256, 0, stream>>>(
      x, memory, W_qkv, W_out, W_rel, v_emb, u_emb,
      Xcat_bf, WqkvT, WoutT, Rrel_bf, vR);

  // 2. qkv = Xcat @ W_qkv  (M=8192, N=1536, K=512), bf16 out,
  //    q third gets (acc + u)*0.125 (u-fold)
  gemm_bf16<<<dim3(12, 64), 256, 0, stream>>>(
      Xcat_bf, WqkvT, 512, 512, 8, qkv_bf, 1536, 1, u_emb);

  // 3. attention (software-pipelined two-tile schedule)
  attn_mfma<<<dim3(32, 8, 8), 256, 0, stream>>>(
      qkv_bf, Rrel_bf, vR, Opart, lbuf);

  // 4. combine split-m partials
  attn_combine<<<1024, 256, 0, stream>>>(Opart, lbuf, aout_bf);

  // 5. out = aout @ W_out + b_out  (M=2048, N=512, K=512), fp32 out, 256 blocks
  gemm_bf16_64<<<dim3(8, 32), 256, 0, stream>>>(
      aout_bf, WoutT, 512, 512, 8, out, 512, b_out);
}